// Round 1
// baseline (376.652 us; speedup 1.0000x reference)
//
#include <hip/hip_runtime.h>

#define BB 2
#define TT 2048
#define CC 768
#define HH 12
#define DD 64
#define TBT (BB * TT)   // 4096 rows

typedef __bf16 bfx8 __attribute__((ext_vector_type(8)));
typedef float f32x4 __attribute__((ext_vector_type(4)));

__device__ __forceinline__ unsigned short f2b(float f) {
  unsigned u = __float_as_uint(f);
  return (unsigned short)((u + 0x7FFFu + ((u >> 16) & 1u)) >> 16);
}

__device__ __forceinline__ void gload_lds16(const void* g, void* l) {
  __builtin_amdgcn_global_load_lds((const __attribute__((address_space(1))) void*)g,
                                   (__attribute__((address_space(3))) void*)l, 16, 0, 0);
}

// ---------------- f32 -> bf16 elementwise (vectorized) ----------------
__global__ __launch_bounds__(256) void k_f32_to_bf16(const float* __restrict__ in,
                                                     unsigned short* __restrict__ out, int n) {
  int i = (blockIdx.x * 256 + threadIdx.x) * 4;
  if (i + 3 < n) {
    float4 v = *(const float4*)(in + i);
    ushort4 o;
    o.x = f2b(v.x); o.y = f2b(v.y); o.z = f2b(v.z); o.w = f2b(v.w);
    *(ushort4*)(out + i) = o;
  }
}

// ---------------- W [K,N] f32  ->  WT [N,K] bf16 (LDS tiled) ----------------
__global__ __launch_bounds__(256) void k_transpose_w(const float* __restrict__ W,
                                                     unsigned short* __restrict__ WT,
                                                     int K, int N) {
  __shared__ float tile[32][33];
  int n0 = blockIdx.x * 32, k0 = blockIdx.y * 32;
  int j = threadIdx.x & 31, i0 = threadIdx.x >> 5;
  for (int i = i0; i < 32; i += 8) tile[i][j] = W[(size_t)(k0 + i) * N + n0 + j];
  __syncthreads();
  for (int i = i0; i < 32; i += 8) WT[(size_t)(n0 + i) * K + k0 + j] = f2b(tile[j][i]);
}

// ---------------- GEMM: C[M,N] = A[M,K] @ B[K,N],  Bt given as [N,K] ----------------
// MODE 0: out = bf16(acc + bias)
// MODE 1: out = bf16(gelu(acc + bias))        (exact erf gelu)
// MODE 2: outf = f32(acc + bias + resid)
template<int MODE>
__global__ __launch_bounds__(256) void k_gemm_bt(const unsigned short* __restrict__ A,
                                                 const unsigned short* __restrict__ Bt,
                                                 const float* __restrict__ bias,
                                                 const float* __restrict__ resid,
                                                 unsigned short* __restrict__ outb,
                                                 float* __restrict__ outf,
                                                 int M, int N, int K) {
  __shared__ __align__(16) unsigned short As[128 * 64];
  __shared__ __align__(16) unsigned short Bs[128 * 64];
  const int tid = threadIdx.x;
  const int l = tid & 63, w = tid >> 6;
  const int wr = w >> 1, wc = w & 1;
  const int lr = l & 15, g = l >> 4;
  const int m0 = blockIdx.y * 128, n0 = blockIdx.x * 128;

  f32x4 acc[4][4] = {};

  for (int kt = 0; kt < K; kt += 64) {
#pragma unroll
    for (int i = 0; i < 4; ++i) {
      int s = tid + i * 256;           // 16B slot index, 0..1023
      int row = s >> 3;
      int q = (s & 7) ^ (row & 7);     // inverse-swizzled global source (linear LDS dest)
      gload_lds16(A + (size_t)(m0 + row) * K + kt + q * 8, &As[s * 8]);
      gload_lds16(Bt + (size_t)(n0 + row) * K + kt + q * 8, &Bs[s * 8]);
    }
    __syncthreads();
#pragma unroll
    for (int kk = 0; kk < 2; ++kk) {
      bfx8 af[4], bfr[4];
#pragma unroll
      for (int m = 0; m < 4; ++m) {
        int row = wr * 64 + m * 16 + lr;
        int quad = (kk * 4 + g) ^ (row & 7);
        af[m] = *(const bfx8*)(&As[row * 64 + quad * 8]);
      }
#pragma unroll
      for (int n = 0; n < 4; ++n) {
        int row = wc * 64 + n * 16 + lr;
        int quad = (kk * 4 + g) ^ (row & 7);
        bfr[n] = *(const bfx8*)(&Bs[row * 64 + quad * 8]);
      }
#pragma unroll
      for (int m = 0; m < 4; ++m)
#pragma unroll
        for (int n = 0; n < 4; ++n)
          acc[m][n] = __builtin_amdgcn_mfma_f32_16x16x32_bf16(af[m], bfr[n], acc[m][n], 0, 0, 0);
    }
    __syncthreads();
  }

#pragma unroll
  for (int m = 0; m < 4; ++m) {
#pragma unroll
    for (int n = 0; n < 4; ++n) {
      int col = n0 + wc * 64 + n * 16 + lr;
      float bv = bias[col];
#pragma unroll
      for (int r = 0; r < 4; ++r) {
        int row = m0 + wr * 64 + m * 16 + g * 4 + r;
        float v = acc[m][n][r] + bv;
        if (MODE == 1) v = 0.5f * v * (1.0f + erff(v * 0.70710678118654752440f));
        if (MODE == 2) {
          v += resid[(size_t)row * N + col];
          outf[(size_t)row * N + col] = v;
        } else {
          outb[(size_t)row * N + col] = f2b(v);
        }
      }
    }
  }
}

// ---------------- V transpose: qkv bf16 -> VT[b,h,d,t] bf16 ----------------
__global__ __launch_bounds__(256) void k_vtrans(const unsigned short* __restrict__ qkv,
                                                unsigned short* __restrict__ VT) {
  int idx = blockIdx.x * 256 + threadIdx.x;   // bh*64*2048 + d*2048 + t
  int t = idx & 2047;
  int rem = idx >> 11;
  int d = rem & 63;
  int bh = rem >> 6;
  int b = bh / HH, h = bh % HH;
  VT[idx] = qkv[(size_t)(b * TT + t) * (3 * CC) + 2 * CC + h * DD + d];
}

// ---------------- causal flash attention (bf16 MFMA) ----------------
__global__ __launch_bounds__(256) void k_attn(const unsigned short* __restrict__ qkv,
                                              const unsigned short* __restrict__ VT,
                                              unsigned short* __restrict__ aout) {
  __shared__ __align__(16) unsigned short plds[4][16 * 64];
  const int tid = threadIdx.x;
  const int l = tid & 63, w = tid >> 6;
  const int lr = l & 15, g = l >> 4;
  const int bh = blockIdx.y;
  const int b = bh / HH, h = bh % HH;
  const int qw = blockIdx.x * 64 + w * 16;   // this wave's 16 q-rows

  bfx8 qf[2];
  {
    const unsigned short* qp = qkv + (size_t)(b * TT + qw + lr) * (3 * CC) + h * DD;
    qf[0] = *(const bfx8*)(qp + g * 8);
    qf[1] = *(const bfx8*)(qp + 32 + g * 8);
  }

  f32x4 o[4] = {};
  float m_r[4] = {-1e30f, -1e30f, -1e30f, -1e30f};
  float l_r[4] = {0.f, 0.f, 0.f, 0.f};

  const int nt = (qw + 16 + 63) >> 6;
  for (int t = 0; t < nt; ++t) {
    const int k0 = t * 64;
    f32x4 s[4];
#pragma unroll
    for (int f = 0; f < 4; ++f) {
      s[f] = (f32x4){0.f, 0.f, 0.f, 0.f};
      const unsigned short* kp = qkv + (size_t)(b * TT + k0 + f * 16 + lr) * (3 * CC) + CC + h * DD;
      bfx8 kf0 = *(const bfx8*)(kp + g * 8);
      bfx8 kf1 = *(const bfx8*)(kp + 32 + g * 8);
      s[f] = __builtin_amdgcn_mfma_f32_16x16x32_bf16(qf[0], kf0, s[f], 0, 0, 0);
      s[f] = __builtin_amdgcn_mfma_f32_16x16x32_bf16(qf[1], kf1, s[f], 0, 0, 0);
    }
    // scale + causal mask + running row max
    float mx[4] = {-1e30f, -1e30f, -1e30f, -1e30f};
#pragma unroll
    for (int f = 0; f < 4; ++f)
#pragma unroll
      for (int r = 0; r < 4; ++r) {
        float sv = s[f][r] * 0.125f;
        bool ok = (k0 + f * 16 + lr) <= (qw + g * 4 + r);
        sv = ok ? sv : -1e30f;
        s[f][r] = sv;
        mx[r] = fmaxf(mx[r], sv);
      }
#pragma unroll
    for (int r = 0; r < 4; ++r) {
#pragma unroll
      for (int off = 1; off < 16; off <<= 1) mx[r] = fmaxf(mx[r], __shfl_xor(mx[r], off));
    }
    float al[4];
#pragma unroll
    for (int r = 0; r < 4; ++r) {
      float mn = fmaxf(m_r[r], mx[r]);
      al[r] = __expf(m_r[r] - mn);
      m_r[r] = mn;
    }
    float rs[4] = {0.f, 0.f, 0.f, 0.f};
#pragma unroll
    for (int f = 0; f < 4; ++f)
#pragma unroll
      for (int r = 0; r < 4; ++r) {
        bool ok = (k0 + f * 16 + lr) <= (qw + g * 4 + r);
        float p = ok ? __expf(s[f][r] - m_r[r]) : 0.0f;   // explicit zero: avoids exp(0)=1 on fully-masked rows
        rs[r] += p;
        int prow = g * 4 + r;
        int quad = (f * 2 + (lr >> 3)) ^ (prow & 7);
        plds[w][prow * 64 + quad * 8 + (lr & 7)] = f2b(p);
      }
#pragma unroll
    for (int r = 0; r < 4; ++r) {
#pragma unroll
      for (int off = 1; off < 16; off <<= 1) rs[r] += __shfl_xor(rs[r], off);
      l_r[r] = l_r[r] * al[r] + rs[r];
#pragma unroll
      for (int n = 0; n < 4; ++n) o[n][r] *= al[r];
    }
    // PV
    bfx8 pf[2];
#pragma unroll
    for (int ks = 0; ks < 2; ++ks) {
      int quad = (ks * 4 + g) ^ (lr & 7);
      pf[ks] = *(const bfx8*)(&plds[w][lr * 64 + quad * 8]);
    }
#pragma unroll
    for (int n = 0; n < 4; ++n) {
      const unsigned short* vp = VT + ((size_t)(bh * DD + n * 16 + lr)) * TT + k0;
      bfx8 vf0 = *(const bfx8*)(vp + g * 8);
      bfx8 vf1 = *(const bfx8*)(vp + 32 + g * 8);
      o[n] = __builtin_amdgcn_mfma_f32_16x16x32_bf16(pf[0], vf0, o[n], 0, 0, 0);
      o[n] = __builtin_amdgcn_mfma_f32_16x16x32_bf16(pf[1], vf1, o[n], 0, 0, 0);
    }
  }

#pragma unroll
  for (int r = 0; r < 4; ++r) {
    float inv = 1.0f / l_r[r];
    int q = qw + g * 4 + r;
#pragma unroll
    for (int n = 0; n < 4; ++n)
      aout[(size_t)(b * TT + q) * CC + h * DD + n * 16 + lr] = f2b(o[n][r] * inv);
  }
}

// ---------------- LayerNorm over C=768, one block per row ----------------
template<int WF32, int WB16>
__global__ __launch_bounds__(256) void k_layernorm(const float* __restrict__ in,
                                                   const float* __restrict__ gw,
                                                   const float* __restrict__ bw,
                                                   float* __restrict__ outf,
                                                   unsigned short* __restrict__ outb) {
  __shared__ float red[8];
  const int row = blockIdx.x;
  const float* x = in + (size_t)row * CC;
  const int tid = threadIdx.x;
  float v[3];
  float s = 0.f;
#pragma unroll
  for (int j = 0; j < 3; ++j) { v[j] = x[tid + j * 256]; s += v[j]; }
#pragma unroll
  for (int off = 32; off; off >>= 1) s += __shfl_xor(s, off);
  if ((tid & 63) == 0) red[tid >> 6] = s;
  __syncthreads();
  s = red[0] + red[1] + red[2] + red[3];
  float mu = s * (1.0f / CC);
  float qs = 0.f;
#pragma unroll
  for (int j = 0; j < 3; ++j) { float d = v[j] - mu; qs += d * d; }
#pragma unroll
  for (int off = 32; off; off >>= 1) qs += __shfl_xor(qs, off);
  if ((tid & 63) == 0) red[4 + (tid >> 6)] = qs;
  __syncthreads();
  qs = red[4] + red[5] + red[6] + red[7];
  float rstd = rsqrtf(qs * (1.0f / CC) + 1e-5f);
#pragma unroll
  for (int j = 0; j < 3; ++j) {
    int c = tid + j * 256;
    float y = (v[j] - mu) * rstd * gw[c] + bw[c];
    if (WF32) outf[(size_t)row * CC + c] = y;
    if (WB16) outb[(size_t)row * CC + c] = f2b(y);
  }
}

extern "C" void kernel_launch(void* const* d_in, const int* in_sizes, int n_in,
                              void* d_out, int out_size, void* d_ws, size_t ws_size,
                              hipStream_t stream) {
  (void)in_sizes; (void)n_in; (void)out_size; (void)ws_size;
  const float* x    = (const float*)d_in[0];
  const float* Wqkv = (const float*)d_in[1];
  const float* bqkv = (const float*)d_in[2];
  const float* Wo   = (const float*)d_in[3];
  const float* bo   = (const float*)d_in[4];
  const float* ln1g = (const float*)d_in[5];
  const float* ln1b = (const float*)d_in[6];
  const float* Wf   = (const float*)d_in[7];
  const float* bf_  = (const float*)d_in[8];
  const float* Wp   = (const float*)d_in[9];
  const float* bp   = (const float*)d_in[10];
  const float* ln2g = (const float*)d_in[11];
  const float* ln2b = (const float*)d_in[12];

  char* ws = (char*)d_ws;
  size_t off = 0;
  auto alloc = [&](size_t bytes) {
    void* p = ws + off;
    off += (bytes + 255) & ~(size_t)255;
    return p;
  };
  unsigned short* xb    = (unsigned short*)alloc((size_t)TBT * CC * 2);
  unsigned short* WqkvT = (unsigned short*)alloc((size_t)3 * CC * CC * 2);
  unsigned short* WoT   = (unsigned short*)alloc((size_t)CC * CC * 2);
  unsigned short* WfT   = (unsigned short*)alloc((size_t)4 * CC * CC * 2);
  unsigned short* WpT   = (unsigned short*)alloc((size_t)4 * CC * CC * 2);
  unsigned short* qkvb  = (unsigned short*)alloc((size_t)TBT * 3 * CC * 2);
  unsigned short* VTb   = (unsigned short*)alloc((size_t)TBT * CC * 2);
  float*          hbuf  = (float*)alloc((size_t)TBT * CC * 4);
  float*          hln   = (float*)alloc((size_t)TBT * CC * 4);
  unsigned short* hlnb  = (unsigned short*)alloc((size_t)TBT * CC * 2);
  unsigned short* gbuf  = (unsigned short*)alloc((size_t)TBT * 4 * CC * 2);
  unsigned short* aout  = xb;    // xb dead after GEMM1
  float*          h2    = hbuf;  // hbuf dead after LN1

  k_f32_to_bf16<<<(TBT * CC) / 1024, 256, 0, stream>>>(x, xb, TBT * CC);
  k_transpose_w<<<dim3(3 * CC / 32, CC / 32), 256, 0, stream>>>(Wqkv, WqkvT, CC, 3 * CC);
  k_transpose_w<<<dim3(CC / 32, CC / 32), 256, 0, stream>>>(Wo, WoT, CC, CC);
  k_transpose_w<<<dim3(4 * CC / 32, CC / 32), 256, 0, stream>>>(Wf, WfT, CC, 4 * CC);
  k_transpose_w<<<dim3(CC / 32, 4 * CC / 32), 256, 0, stream>>>(Wp, WpT, 4 * CC, CC);

  // qkv = x @ Wqkv + bqkv   -> bf16 [4096, 2304]
  k_gemm_bt<0><<<dim3(3 * CC / 128, TBT / 128), 256, 0, stream>>>(
      xb, WqkvT, bqkv, nullptr, qkvb, nullptr, TBT, 3 * CC, CC);
  // VT[b,h,d,t]
  k_vtrans<<<(TBT * CC) / 256, 256, 0, stream>>>(qkvb, VTb);
  // attention -> aout bf16 [4096, 768]
  k_attn<<<dim3(TT / 64, BB * HH), 256, 0, stream>>>(qkvb, VTb, aout);
  // h = x + attn @ Wo + bo  -> f32
  k_gemm_bt<2><<<dim3(CC / 128, TBT / 128), 256, 0, stream>>>(
      aout, WoT, bo, x, nullptr, hbuf, TBT, CC, CC);
  // LN1 -> hln (f32) + hlnb (bf16)
  k_layernorm<1, 1><<<TBT, 256, 0, stream>>>(hbuf, ln1g, ln1b, hln, hlnb);
  // g = gelu(hln @ Wf + bf) -> bf16 [4096, 3072]
  k_gemm_bt<1><<<dim3(4 * CC / 128, TBT / 128), 256, 0, stream>>>(
      hlnb, WfT, bf_, nullptr, gbuf, nullptr, TBT, 4 * CC, CC);
  // h2 = hln + g @ Wp + bp  -> f32
  k_gemm_bt<2><<<dim3(CC / 128, TBT / 128), 256, 0, stream>>>(
      gbuf, WpT, bp, hln, nullptr, h2, TBT, CC, 4 * CC);
  // LN2 -> d_out (f32)
  k_layernorm<1, 0><<<TBT, 256, 0, stream>>>(h2, ln2g, ln2b, (float*)d_out, nullptr);
}

// Round 2
// 282.532 us; speedup vs baseline: 1.3331x; 1.3331x over previous
//
#include <hip/hip_runtime.h>

#define BB 2
#define TT 2048
#define CC 768
#define HH 12
#define DD 64
#define TBT (BB * TT)   // 4096 rows

typedef __bf16 bfx8 __attribute__((ext_vector_type(8)));
typedef float f32x4 __attribute__((ext_vector_type(4)));

__device__ __forceinline__ unsigned short f2b(float f) {
  unsigned u = __float_as_uint(f);
  return (unsigned short)((u + 0x7FFFu + ((u >> 16) & 1u)) >> 16);
}

__device__ __forceinline__ void gload_lds16(const void* g, void* l) {
  __builtin_amdgcn_global_load_lds((const __attribute__((address_space(1))) void*)g,
                                   (__attribute__((address_space(3))) void*)l, 16, 0, 0);
}

// ---------------- f32 -> bf16 elementwise (vectorized) ----------------
__global__ __launch_bounds__(256) void k_f32_to_bf16(const float* __restrict__ in,
                                                     unsigned short* __restrict__ out, int n) {
  int i = (blockIdx.x * 256 + threadIdx.x) * 4;
  if (i + 3 < n) {
    float4 v = *(const float4*)(in + i);
    ushort4 o;
    o.x = f2b(v.x); o.y = f2b(v.y); o.z = f2b(v.z); o.w = f2b(v.w);
    *(ushort4*)(out + i) = o;
  }
}

// ---------------- W [K,N] f32  ->  WT [N,K] bf16 (LDS tiled) ----------------
__global__ __launch_bounds__(256) void k_transpose_w(const float* __restrict__ W,
                                                     unsigned short* __restrict__ WT,
                                                     int K, int N) {
  __shared__ float tile[32][33];
  int n0 = blockIdx.x * 32, k0 = blockIdx.y * 32;
  int j = threadIdx.x & 31, i0 = threadIdx.x >> 5;
  for (int i = i0; i < 32; i += 8) tile[i][j] = W[(size_t)(k0 + i) * N + n0 + j];
  __syncthreads();
  for (int i = i0; i < 32; i += 8) WT[(size_t)(n0 + i) * K + k0 + j] = f2b(tile[j][i]);
}

// ---------------- GEMM: C[M,N] = A[M,K] @ B[K,N],  Bt given as [N,K] ----------------
// MODE 0: out = bf16(acc + bias)
// MODE 1: out = bf16(gelu(acc + bias))        (exact erf gelu)
// MODE 2: outf = f32(acc + bias + resid)
template<int MODE>
__global__ __launch_bounds__(256) void k_gemm_bt(const unsigned short* __restrict__ A,
                                                 const unsigned short* __restrict__ Bt,
                                                 const float* __restrict__ bias,
                                                 const float* __restrict__ resid,
                                                 unsigned short* __restrict__ outb,
                                                 float* __restrict__ outf,
                                                 int M, int N, int K) {
  __shared__ __align__(16) unsigned short As[128 * 64];
  __shared__ __align__(16) unsigned short Bs[128 * 64];
  const int tid = threadIdx.x;
  const int l = tid & 63, w = tid >> 6;
  const int wr = w >> 1, wc = w & 1;
  const int lr = l & 15, g = l >> 4;
  const int m0 = blockIdx.y * 128, n0 = blockIdx.x * 128;

  f32x4 acc[4][4] = {};

  for (int kt = 0; kt < K; kt += 64) {
#pragma unroll
    for (int i = 0; i < 4; ++i) {
      int s = tid + i * 256;           // 16B slot index, 0..1023
      int row = s >> 3;
      int q = (s & 7) ^ (row & 7);     // inverse-swizzled global source (linear LDS dest)
      gload_lds16(A + (size_t)(m0 + row) * K + kt + q * 8, &As[s * 8]);
      gload_lds16(Bt + (size_t)(n0 + row) * K + kt + q * 8, &Bs[s * 8]);
    }
    __syncthreads();
#pragma unroll
    for (int kk = 0; kk < 2; ++kk) {
      bfx8 af[4], bfr[4];
#pragma unroll
      for (int m = 0; m < 4; ++m) {
        int row = wr * 64 + m * 16 + lr;
        int quad = (kk * 4 + g) ^ (row & 7);
        af[m] = *(const bfx8*)(&As[row * 64 + quad * 8]);
      }
#pragma unroll
      for (int n = 0; n < 4; ++n) {
        int row = wc * 64 + n * 16 + lr;
        int quad = (kk * 4 + g) ^ (row & 7);
        bfr[n] = *(const bfx8*)(&Bs[row * 64 + quad * 8]);
      }
#pragma unroll
      for (int m = 0; m < 4; ++m)
#pragma unroll
        for (int n = 0; n < 4; ++n)
          acc[m][n] = __builtin_amdgcn_mfma_f32_16x16x32_bf16(af[m], bfr[n], acc[m][n], 0, 0, 0);
    }
    __syncthreads();
  }

#pragma unroll
  for (int m = 0; m < 4; ++m) {
#pragma unroll
    for (int n = 0; n < 4; ++n) {
      int col = n0 + wc * 64 + n * 16 + lr;
      float bv = bias[col];
#pragma unroll
      for (int r = 0; r < 4; ++r) {
        int row = m0 + wr * 64 + m * 16 + g * 4 + r;
        float v = acc[m][n][r] + bv;
        if (MODE == 1) v = 0.5f * v * (1.0f + erff(v * 0.70710678118654752440f));
        if (MODE == 2) {
          v += resid[(size_t)row * N + col];
          outf[(size_t)row * N + col] = v;
        } else {
          outb[(size_t)row * N + col] = f2b(v);
        }
      }
    }
  }
}

// ---------------- V transpose (LDS tiled): qkv bf16 -> VT[b,h,d,t] bf16 ----------------
__global__ __launch_bounds__(256) void k_vtrans(const unsigned short* __restrict__ qkv,
                                                unsigned short* __restrict__ VT) {
  __shared__ unsigned short tile[32][33];
  int t0 = blockIdx.x * 32, d0 = blockIdx.y * 32, bh = blockIdx.z;
  int b = bh / HH, h = bh % HH;
  int j = threadIdx.x & 31, i0 = threadIdx.x >> 5;
  for (int i = i0; i < 32; i += 8)
    tile[i][j] = qkv[(size_t)(b * TT + t0 + i) * (3 * CC) + 2 * CC + h * DD + d0 + j];
  __syncthreads();
  for (int i = i0; i < 32; i += 8)
    VT[((size_t)(bh * DD + d0 + i)) * TT + t0 + j] = tile[j][i];
}

// ---------------- causal flash attention (bf16 MFMA, LDS-staged K/V, 2-phase dbuf) ----------------
__global__ __launch_bounds__(256) void k_attn(const unsigned short* __restrict__ qkv,
                                              const unsigned short* __restrict__ VT,
                                              unsigned short* __restrict__ aout) {
  __shared__ __align__(16) unsigned short Ks[2][64 * 64];
  __shared__ __align__(16) unsigned short Vs[2][64 * 64];
  __shared__ __align__(16) unsigned short plds[4][16 * 64];
  const int tid = threadIdx.x;
  const int l = tid & 63, w = tid >> 6;
  const int lr = l & 15, g = l >> 4;
  const int bh = blockIdx.y;
  const int b = bh / HH, h = bh % HH;
  const int q0 = blockIdx.x * 64;
  const int qw = q0 + w * 16;   // this wave's 16 q-rows

  const unsigned short* Kbase = qkv + (size_t)(b * TT) * (3 * CC) + CC + h * DD;
  const unsigned short* Vbase = VT + (size_t)bh * DD * TT;

  bfx8 qf[2];
  {
    const unsigned short* qp = qkv + (size_t)(b * TT + qw + lr) * (3 * CC) + h * DD;
    qf[0] = *(const bfx8*)(qp + g * 8);
    qf[1] = *(const bfx8*)(qp + 32 + g * 8);
  }

  f32x4 o[4] = {};
  float m_r[4] = {-1e30f, -1e30f, -1e30f, -1e30f};
  float l_r[4] = {0.f, 0.f, 0.f, 0.f};

  const int nt = blockIdx.x + 1;   // k-tiles 0..blockIdx.x cover all q rows of this block

  auto stage = [&](int t, int bufi) {
    const int k0 = t * 64;
#pragma unroll
    for (int i = 0; i < 2; ++i) {
      int s = tid + i * 256;          // 16B slot, 0..511
      int row = s >> 3;
      int q = (s & 7) ^ (row & 7);    // inverse-swizzled source, linear LDS dest
      gload_lds16(Kbase + (size_t)(k0 + row) * (3 * CC) + q * 8, &Ks[bufi][s * 8]);
      gload_lds16(Vbase + (size_t)row * TT + k0 + q * 8, &Vs[bufi][s * 8]);
    }
  };

  stage(0, 0);
  __syncthreads();

  int cur = 0;
  for (int t = 0; t < nt; ++t) {
    const int k0 = t * 64;
    if (t + 1 < nt) stage(t + 1, cur ^ 1);   // prefetch overlaps compute below

    // ---- QK^T from LDS ----
    f32x4 s[4];
#pragma unroll
    for (int f = 0; f < 4; ++f) {
      s[f] = (f32x4){0.f, 0.f, 0.f, 0.f};
      int row = f * 16 + lr;
      bfx8 kf0 = *(const bfx8*)(&Ks[cur][row * 64 + ((g ^ (row & 7)) * 8)]);
      bfx8 kf1 = *(const bfx8*)(&Ks[cur][row * 64 + (((4 + g) ^ (row & 7)) * 8)]);
      s[f] = __builtin_amdgcn_mfma_f32_16x16x32_bf16(qf[0], kf0, s[f], 0, 0, 0);
      s[f] = __builtin_amdgcn_mfma_f32_16x16x32_bf16(qf[1], kf1, s[f], 0, 0, 0);
    }

    // ---- scale + causal mask + running row max ----
    float mx[4] = {-1e30f, -1e30f, -1e30f, -1e30f};
#pragma unroll
    for (int f = 0; f < 4; ++f)
#pragma unroll
      for (int r = 0; r < 4; ++r) {
        float sv = s[f][r] * 0.125f;
        bool ok = (k0 + f * 16 + lr) <= (qw + g * 4 + r);
        sv = ok ? sv : -1e30f;
        s[f][r] = sv;
        mx[r] = fmaxf(mx[r], sv);
      }
#pragma unroll
    for (int r = 0; r < 4; ++r) {
#pragma unroll
      for (int off = 1; off < 16; off <<= 1) mx[r] = fmaxf(mx[r], __shfl_xor(mx[r], off));
    }
    float al[4];
#pragma unroll
    for (int r = 0; r < 4; ++r) {
      float mn = fmaxf(m_r[r], mx[r]);
      al[r] = __expf(m_r[r] - mn);
      m_r[r] = mn;
    }
    float rs[4] = {0.f, 0.f, 0.f, 0.f};
#pragma unroll
    for (int f = 0; f < 4; ++f)
#pragma unroll
      for (int r = 0; r < 4; ++r) {
        bool ok = (k0 + f * 16 + lr) <= (qw + g * 4 + r);
        float p = ok ? __expf(s[f][r] - m_r[r]) : 0.0f;
        rs[r] += p;
        int prow = g * 4 + r;
        int quad = (f * 2 + (lr >> 3)) ^ (prow & 7);
        plds[w][prow * 64 + quad * 8 + (lr & 7)] = f2b(p);
      }
#pragma unroll
    for (int r = 0; r < 4; ++r) {
#pragma unroll
      for (int off = 1; off < 16; off <<= 1) rs[r] += __shfl_xor(rs[r], off);
      l_r[r] = l_r[r] * al[r] + rs[r];
#pragma unroll
      for (int n = 0; n < 4; ++n) o[n][r] *= al[r];
    }

    // ---- PV from LDS ----
    bfx8 pf[2];
#pragma unroll
    for (int ks = 0; ks < 2; ++ks) {
      int quad = (ks * 4 + g) ^ (lr & 7);
      pf[ks] = *(const bfx8*)(&plds[w][lr * 64 + quad * 8]);
    }
#pragma unroll
    for (int n = 0; n < 4; ++n) {
      int row = n * 16 + lr;
      bfx8 vf0 = *(const bfx8*)(&Vs[cur][row * 64 + ((g ^ (row & 7)) * 8)]);
      bfx8 vf1 = *(const bfx8*)(&Vs[cur][row * 64 + (((4 + g) ^ (row & 7)) * 8)]);
      o[n] = __builtin_amdgcn_mfma_f32_16x16x32_bf16(pf[0], vf0, o[n], 0, 0, 0);
      o[n] = __builtin_amdgcn_mfma_f32_16x16x32_bf16(pf[1], vf1, o[n], 0, 0, 0);
    }

    __syncthreads();   // drains prefetch (vmcnt) + all waves done reading buf[cur]
    cur ^= 1;
  }

#pragma unroll
  for (int r = 0; r < 4; ++r) {
    float inv = 1.0f / l_r[r];
    int q = qw + g * 4 + r;
#pragma unroll
    for (int n = 0; n < 4; ++n)
      aout[(size_t)(b * TT + q) * CC + h * DD + n * 16 + lr] = f2b(o[n][r] * inv);
  }
}

// ---------------- LayerNorm over C=768, one block per row ----------------
template<int WF32, int WB16>
__global__ __launch_bounds__(256) void k_layernorm(const float* __restrict__ in,
                                                   const float* __restrict__ gw,
                                                   const float* __restrict__ bw,
                                                   float* __restrict__ outf,
                                                   unsigned short* __restrict__ outb) {
  __shared__ float red[8];
  const int row = blockIdx.x;
  const float* x = in + (size_t)row * CC;
  const int tid = threadIdx.x;
  float v[3];
  float s = 0.f;
#pragma unroll
  for (int j = 0; j < 3; ++j) { v[j] = x[tid + j * 256]; s += v[j]; }
#pragma unroll
  for (int off = 32; off; off >>= 1) s += __shfl_xor(s, off);
  if ((tid & 63) == 0) red[tid >> 6] = s;
  __syncthreads();
  s = red[0] + red[1] + red[2] + red[3];
  float mu = s * (1.0f / CC);
  float qs = 0.f;
#pragma unroll
  for (int j = 0; j < 3; ++j) { float d = v[j] - mu; qs += d * d; }
#pragma unroll
  for (int off = 32; off; off >>= 1) qs += __shfl_xor(qs, off);
  if ((tid & 63) == 0) red[4 + (tid >> 6)] = qs;
  __syncthreads();
  qs = red[4] + red[5] + red[6] + red[7];
  float rstd = rsqrtf(qs * (1.0f / CC) + 1e-5f);
#pragma unroll
  for (int j = 0; j < 3; ++j) {
    int c = tid + j * 256;
    float y = (v[j] - mu) * rstd * gw[c] + bw[c];
    if (WF32) outf[(size_t)row * CC + c] = y;
    if (WB16) outb[(size_t)row * CC + c] = f2b(y);
  }
}

extern "C" void kernel_launch(void* const* d_in, const int* in_sizes, int n_in,
                              void* d_out, int out_size, void* d_ws, size_t ws_size,
                              hipStream_t stream) {
  (void)in_sizes; (void)n_in; (void)out_size; (void)ws_size;
  const float* x    = (const float*)d_in[0];
  const float* Wqkv = (const float*)d_in[1];
  const float* bqkv = (const float*)d_in[2];
  const float* Wo   = (const float*)d_in[3];
  const float* bo   = (const float*)d_in[4];
  const float* ln1g = (const float*)d_in[5];
  const float* ln1b = (const float*)d_in[6];
  const float* Wf   = (const float*)d_in[7];
  const float* bf_  = (const float*)d_in[8];
  const float* Wp   = (const float*)d_in[9];
  const float* bp   = (const float*)d_in[10];
  const float* ln2g = (const float*)d_in[11];
  const float* ln2b = (const float*)d_in[12];

  char* ws = (char*)d_ws;
  size_t off = 0;
  auto alloc = [&](size_t bytes) {
    void* p = ws + off;
    off += (bytes + 255) & ~(size_t)255;
    return p;
  };
  unsigned short* xb    = (unsigned short*)alloc((size_t)TBT * CC * 2);
  unsigned short* WqkvT = (unsigned short*)alloc((size_t)3 * CC * CC * 2);
  unsigned short* WoT   = (unsigned short*)alloc((size_t)CC * CC * 2);
  unsigned short* WfT   = (unsigned short*)alloc((size_t)4 * CC * CC * 2);
  unsigned short* WpT   = (unsigned short*)alloc((size_t)4 * CC * CC * 2);
  unsigned short* qkvb  = (unsigned short*)alloc((size_t)TBT * 3 * CC * 2);
  unsigned short* VTb   = (unsigned short*)alloc((size_t)TBT * CC * 2);
  float*          hbuf  = (float*)alloc((size_t)TBT * CC * 4);
  float*          hln   = (float*)alloc((size_t)TBT * CC * 4);
  unsigned short* hlnb  = (unsigned short*)alloc((size_t)TBT * CC * 2);
  unsigned short* gbuf  = (unsigned short*)alloc((size_t)TBT * 4 * CC * 2);
  unsigned short* aout  = xb;    // xb dead after GEMM1
  float*          h2    = hbuf;  // hbuf dead after LN1

  k_f32_to_bf16<<<(TBT * CC) / 1024, 256, 0, stream>>>(x, xb, TBT * CC);
  k_transpose_w<<<dim3(3 * CC / 32, CC / 32), 256, 0, stream>>>(Wqkv, WqkvT, CC, 3 * CC);
  k_transpose_w<<<dim3(CC / 32, CC / 32), 256, 0, stream>>>(Wo, WoT, CC, CC);
  k_transpose_w<<<dim3(4 * CC / 32, CC / 32), 256, 0, stream>>>(Wf, WfT, CC, 4 * CC);
  k_transpose_w<<<dim3(CC / 32, 4 * CC / 32), 256, 0, stream>>>(Wp, WpT, 4 * CC, CC);

  // qkv = x @ Wqkv + bqkv   -> bf16 [4096, 2304]
  k_gemm_bt<0><<<dim3(3 * CC / 128, TBT / 128), 256, 0, stream>>>(
      xb, WqkvT, bqkv, nullptr, qkvb, nullptr, TBT, 3 * CC, CC);
  // VT[b,h,d,t]
  k_vtrans<<<dim3(TT / 32, DD / 32, BB * HH), 256, 0, stream>>>(qkvb, VTb);
  // attention -> aout bf16 [4096, 768]
  k_attn<<<dim3(TT / 64, BB * HH), 256, 0, stream>>>(qkvb, VTb, aout);
  // h = x + attn @ Wo + bo  -> f32
  k_gemm_bt<2><<<dim3(CC / 128, TBT / 128), 256, 0, stream>>>(
      aout, WoT, bo, x, nullptr, hbuf, TBT, CC, CC);
  // LN1 -> hln (f32) + hlnb (bf16)
  k_layernorm<1, 1><<<TBT, 256, 0, stream>>>(hbuf, ln1g, ln1b, hln, hlnb);
  // g = gelu(hln @ Wf + bf) -> bf16 [4096, 3072]
  k_gemm_bt<1><<<dim3(4 * CC / 128, TBT / 128), 256, 0, stream>>>(
      hlnb, WfT, bf_, nullptr, gbuf, nullptr, TBT, 4 * CC, CC);
  // h2 = hln + g @ Wp + bp  -> f32
  k_gemm_bt<2><<<dim3(CC / 128, TBT / 128), 256, 0, stream>>>(
      gbuf, WpT, bp, hln, nullptr, h2, TBT, CC, 4 * CC);
  // LN2 -> d_out (f32)
  k_layernorm<1, 0><<<TBT, 256, 0, stream>>>(h2, ln2g, ln2b, (float*)d_out, nullptr);
}

// Round 3
// 274.524 us; speedup vs baseline: 1.3720x; 1.0292x over previous
//
#include <hip/hip_runtime.h>

#define BB 2
#define TT 2048
#define CC 768
#define HH 12
#define DD 64
#define TBT (BB * TT)   // 4096 rows

typedef __bf16 bfx8 __attribute__((ext_vector_type(8)));
typedef float f32x4 __attribute__((ext_vector_type(4)));

__device__ __forceinline__ unsigned short f2b(float f) {
  unsigned u = __float_as_uint(f);
  return (unsigned short)((u + 0x7FFFu + ((u >> 16) & 1u)) >> 16);
}

__device__ __forceinline__ void gload_lds16(const void* g, void* l) {
  __builtin_amdgcn_global_load_lds((const __attribute__((address_space(1))) void*)g,
                                   (__attribute__((address_space(3))) void*)l, 16, 0, 0);
}

// ---------------- f32 -> bf16 elementwise (vectorized) ----------------
__global__ __launch_bounds__(256) void k_f32_to_bf16(const float* __restrict__ in,
                                                     unsigned short* __restrict__ out, int n) {
  int i = (blockIdx.x * 256 + threadIdx.x) * 4;
  if (i + 3 < n) {
    float4 v = *(const float4*)(in + i);
    ushort4 o;
    o.x = f2b(v.x); o.y = f2b(v.y); o.z = f2b(v.z); o.w = f2b(v.w);
    *(ushort4*)(out + i) = o;
  }
}

// ---------------- W [K,N] f32  ->  WT [N,K] bf16 (LDS tiled) ----------------
__global__ __launch_bounds__(256) void k_transpose_w(const float* __restrict__ W,
                                                     unsigned short* __restrict__ WT,
                                                     int K, int N) {
  __shared__ float tile[32][33];
  int n0 = blockIdx.x * 32, k0 = blockIdx.y * 32;
  int j = threadIdx.x & 31, i0 = threadIdx.x >> 5;
  for (int i = i0; i < 32; i += 8) tile[i][j] = W[(size_t)(k0 + i) * N + n0 + j];
  __syncthreads();
  for (int i = i0; i < 32; i += 8) WT[(size_t)(n0 + i) * K + k0 + j] = f2b(tile[j][i]);
}

// ---------------- GEMM: C[M,N] = A[M,K] @ B[K,N],  Bt given as [N,K] ----------------
// MODE 0: out = bf16(acc + bias)
// MODE 1: out = bf16(gelu(acc + bias))        (exact erf gelu)
// MODE 2: outf = f32(acc + bias + resid)
template<int MODE>
__global__ __launch_bounds__(256) void k_gemm_bt(const unsigned short* __restrict__ A,
                                                 const unsigned short* __restrict__ Bt,
                                                 const float* __restrict__ bias,
                                                 const float* __restrict__ resid,
                                                 unsigned short* __restrict__ outb,
                                                 float* __restrict__ outf,
                                                 int M, int N, int K) {
  __shared__ __align__(16) unsigned short As[128 * 64];
  __shared__ __align__(16) unsigned short Bs[128 * 64];
  const int tid = threadIdx.x;
  const int l = tid & 63, w = tid >> 6;
  const int wr = w >> 1, wc = w & 1;
  const int lr = l & 15, g = l >> 4;
  const int m0 = blockIdx.y * 128, n0 = blockIdx.x * 128;

  f32x4 acc[4][4] = {};

  for (int kt = 0; kt < K; kt += 64) {
#pragma unroll
    for (int i = 0; i < 4; ++i) {
      int s = tid + i * 256;           // 16B slot index, 0..1023
      int row = s >> 3;
      int q = (s & 7) ^ (row & 7);     // inverse-swizzled global source (linear LDS dest)
      gload_lds16(A + (size_t)(m0 + row) * K + kt + q * 8, &As[s * 8]);
      gload_lds16(Bt + (size_t)(n0 + row) * K + kt + q * 8, &Bs[s * 8]);
    }
    __syncthreads();
#pragma unroll
    for (int kk = 0; kk < 2; ++kk) {
      bfx8 af[4], bfr[4];
#pragma unroll
      for (int m = 0; m < 4; ++m) {
        int row = wr * 64 + m * 16 + lr;
        int quad = (kk * 4 + g) ^ (row & 7);
        af[m] = *(const bfx8*)(&As[row * 64 + quad * 8]);
      }
#pragma unroll
      for (int n = 0; n < 4; ++n) {
        int row = wc * 64 + n * 16 + lr;
        int quad = (kk * 4 + g) ^ (row & 7);
        bfr[n] = *(const bfx8*)(&Bs[row * 64 + quad * 8]);
      }
#pragma unroll
      for (int m = 0; m < 4; ++m)
#pragma unroll
        for (int n = 0; n < 4; ++n)
          acc[m][n] = __builtin_amdgcn_mfma_f32_16x16x32_bf16(af[m], bfr[n], acc[m][n], 0, 0, 0);
    }
    __syncthreads();
  }

#pragma unroll
  for (int m = 0; m < 4; ++m) {
#pragma unroll
    for (int n = 0; n < 4; ++n) {
      int col = n0 + wc * 64 + n * 16 + lr;
      float bv = bias[col];
#pragma unroll
      for (int r = 0; r < 4; ++r) {
        int row = m0 + wr * 64 + m * 16 + g * 4 + r;
        float v = acc[m][n][r] + bv;
        if (MODE == 1) v = 0.5f * v * (1.0f + erff(v * 0.70710678118654752440f));
        if (MODE == 2) {
          v += resid[(size_t)row * N + col];
          outf[(size_t)row * N + col] = v;
        } else {
          outb[(size_t)row * N + col] = f2b(v);
        }
      }
    }
  }
}

// ---------------- V transpose (LDS tiled): qkv bf16 -> VT[b,h,d,t] bf16 ----------------
__global__ __launch_bounds__(256) void k_vtrans(const unsigned short* __restrict__ qkv,
                                                unsigned short* __restrict__ VT) {
  __shared__ unsigned short tile[32][33];
  int t0 = blockIdx.x * 32, d0 = blockIdx.y * 32, bh = blockIdx.z;
  int b = bh / HH, h = bh % HH;
  int j = threadIdx.x & 31, i0 = threadIdx.x >> 5;
  for (int i = i0; i < 32; i += 8)
    tile[i][j] = qkv[(size_t)(b * TT + t0 + i) * (3 * CC) + 2 * CC + h * DD + d0 + j];
  __syncthreads();
  for (int i = i0; i < 32; i += 8)
    VT[((size_t)(bh * DD + d0 + i)) * TT + t0 + j] = tile[j][i];
}

// ---------------- causal flash attention (bf16 MFMA, LDS-staged K/V, 2-phase dbuf) ----------------
// log2-domain softmax: Q pre-scaled by 0.125*log2e, p = exp2(s - m), defer-max rescale.
__global__ __launch_bounds__(256) void k_attn(const unsigned short* __restrict__ qkv,
                                              const unsigned short* __restrict__ VT,
                                              unsigned short* __restrict__ aout) {
  __shared__ __align__(16) unsigned short Ks[2][64 * 64];
  __shared__ __align__(16) unsigned short Vs[2][64 * 64];
  __shared__ __align__(16) unsigned short plds[4][16 * 64];
  const int tid = threadIdx.x;
  const int l = tid & 63, w = tid >> 6;
  const int lr = l & 15, g = l >> 4;
  const int bh = blockIdx.y;
  const int b = bh / HH, h = bh % HH;
  // balance swizzle: consecutive blockIdx.x get (long, short) tiles pairing to ~equal work per CU
  const int tx = blockIdx.x;
  const int bx = (tx & 1) ? ((int)gridDim.x - 1 - (tx >> 1)) : (tx >> 1);
  const int q0 = bx * 64;
  const int qw = q0 + w * 16;   // this wave's 16 q-rows

  const unsigned short* Kbase = qkv + (size_t)(b * TT) * (3 * CC) + CC + h * DD;
  const unsigned short* Vbase = VT + (size_t)bh * DD * TT;

  bfx8 qf[2];
  {
    const unsigned short* qp = qkv + (size_t)(b * TT + qw + lr) * (3 * CC) + h * DD;
    bfx8 r0 = *(const bfx8*)(qp + g * 8);
    bfx8 r1 = *(const bfx8*)(qp + 32 + g * 8);
    const float SC = 0.125f * 1.44269504088896340736f;   // 1/sqrt(D) * log2(e)
#pragma unroll
    for (int j = 0; j < 8; ++j) {
      qf[0][j] = (__bf16)((float)r0[j] * SC);
      qf[1][j] = (__bf16)((float)r1[j] * SC);
    }
  }

  f32x4 o[4] = {};
  float m_r[4] = {-1e30f, -1e30f, -1e30f, -1e30f};
  float l_r[4] = {0.f, 0.f, 0.f, 0.f};

  const int nt = bx + 1;   // k-tiles 0..bx cover all q rows of this block

  auto stage = [&](int t, int bufi) {
    const int k0 = t * 64;
#pragma unroll
    for (int i = 0; i < 2; ++i) {
      int s = tid + i * 256;          // 16B slot, 0..511
      int row = s >> 3;
      int q = (s & 7) ^ (row & 7);    // inverse-swizzled source, linear LDS dest
      gload_lds16(Kbase + (size_t)(k0 + row) * (3 * CC) + q * 8, &Ks[bufi][s * 8]);
      gload_lds16(Vbase + (size_t)row * TT + k0 + q * 8, &Vs[bufi][s * 8]);
    }
  };

  stage(0, 0);
  __syncthreads();

  int cur = 0;
  for (int t = 0; t < nt; ++t) {
    const int k0 = t * 64;
    if (t + 1 < nt) stage(t + 1, cur ^ 1);   // prefetch overlaps compute below

    // ---- QK^T from LDS (Q pre-scaled: s is in log2 domain) ----
    f32x4 s[4];
    __builtin_amdgcn_s_setprio(1);
#pragma unroll
    for (int f = 0; f < 4; ++f) {
      s[f] = (f32x4){0.f, 0.f, 0.f, 0.f};
      int row = f * 16 + lr;
      bfx8 kf0 = *(const bfx8*)(&Ks[cur][row * 64 + ((g ^ (row & 7)) * 8)]);
      bfx8 kf1 = *(const bfx8*)(&Ks[cur][row * 64 + (((4 + g) ^ (row & 7)) * 8)]);
      s[f] = __builtin_amdgcn_mfma_f32_16x16x32_bf16(qf[0], kf0, s[f], 0, 0, 0);
      s[f] = __builtin_amdgcn_mfma_f32_16x16x32_bf16(qf[1], kf1, s[f], 0, 0, 0);
    }
    __builtin_amdgcn_s_setprio(0);

    // ---- causal mask: only the diagonal tile needs it (wave-uniform branch) ----
    if (t == nt - 1) {
#pragma unroll
      for (int f = 0; f < 4; ++f)
#pragma unroll
        for (int r = 0; r < 4; ++r) {
          bool ok = (k0 + f * 16 + lr) <= (qw + g * 4 + r);
          s[f][r] = ok ? s[f][r] : -1e30f;
        }
    }

    // ---- per-row tile max (in-lane tree + 16-lane shfl reduce) ----
    float mx[4];
#pragma unroll
    for (int r = 0; r < 4; ++r)
      mx[r] = fmaxf(fmaxf(s[0][r], s[1][r]), fmaxf(s[2][r], s[3][r]));
#pragma unroll
    for (int r = 0; r < 4; ++r) {
#pragma unroll
      for (int off = 1; off < 16; off <<= 1) mx[r] = fmaxf(mx[r], __shfl_xor(mx[r], off));
    }

    // ---- defer-max: rescale only when the row max actually grows (log2 thr ~ e^8) ----
    bool need = false;
#pragma unroll
    for (int r = 0; r < 4; ++r) need = need || (mx[r] > m_r[r] + 11.0f);
    if (__any(need)) {
#pragma unroll
      for (int r = 0; r < 4; ++r) {
        float mn = fmaxf(m_r[r], mx[r]);
        float al = __builtin_amdgcn_exp2f(m_r[r] - mn);
        m_r[r] = mn;
        l_r[r] *= al;
#pragma unroll
        for (int n = 0; n < 4; ++n) o[n][r] *= al;
      }
    }

    // ---- p = exp2(s - m); masked elements underflow to 0 automatically ----
    float rs[4] = {0.f, 0.f, 0.f, 0.f};
#pragma unroll
    for (int f = 0; f < 4; ++f)
#pragma unroll
      for (int r = 0; r < 4; ++r) {
        float p = __builtin_amdgcn_exp2f(s[f][r] - m_r[r]);
        rs[r] += p;
        int prow = g * 4 + r;
        int quad = (f * 2 + (lr >> 3)) ^ (prow & 7);
        plds[w][prow * 64 + quad * 8 + (lr & 7)] = f2b(p);
      }
#pragma unroll
    for (int r = 0; r < 4; ++r) {
#pragma unroll
      for (int off = 1; off < 16; off <<= 1) rs[r] += __shfl_xor(rs[r], off);
      l_r[r] += rs[r];
    }

    // ---- PV from LDS ----
    bfx8 pf[2];
#pragma unroll
    for (int ks = 0; ks < 2; ++ks) {
      int quad = (ks * 4 + g) ^ (lr & 7);
      pf[ks] = *(const bfx8*)(&plds[w][lr * 64 + quad * 8]);
    }
    __builtin_amdgcn_s_setprio(1);
#pragma unroll
    for (int n = 0; n < 4; ++n) {
      int row = n * 16 + lr;
      bfx8 vf0 = *(const bfx8*)(&Vs[cur][row * 64 + ((g ^ (row & 7)) * 8)]);
      bfx8 vf1 = *(const bfx8*)(&Vs[cur][row * 64 + (((4 + g) ^ (row & 7)) * 8)]);
      o[n] = __builtin_amdgcn_mfma_f32_16x16x32_bf16(pf[0], vf0, o[n], 0, 0, 0);
      o[n] = __builtin_amdgcn_mfma_f32_16x16x32_bf16(pf[1], vf1, o[n], 0, 0, 0);
    }
    __builtin_amdgcn_s_setprio(0);

    __syncthreads();   // drains prefetch (vmcnt) + all waves done reading buf[cur]
    cur ^= 1;
  }

#pragma unroll
  for (int r = 0; r < 4; ++r) {
    float inv = 1.0f / l_r[r];
    int q = qw + g * 4 + r;
#pragma unroll
    for (int n = 0; n < 4; ++n)
      aout[(size_t)(b * TT + q) * CC + h * DD + n * 16 + lr] = f2b(o[n][r] * inv);
  }
}

// ---------------- LayerNorm over C=768, one block per row ----------------
template<int WF32, int WB16>
__global__ __launch_bounds__(256) void k_layernorm(const float* __restrict__ in,
                                                   const float* __restrict__ gw,
                                                   const float* __restrict__ bw,
                                                   float* __restrict__ outf,
                                                   unsigned short* __restrict__ outb) {
  __shared__ float red[8];
  const int row = blockIdx.x;
  const float* x = in + (size_t)row * CC;
  const int tid = threadIdx.x;
  float v[3];
  float s = 0.f;
#pragma unroll
  for (int j = 0; j < 3; ++j) { v[j] = x[tid + j * 256]; s += v[j]; }
#pragma unroll
  for (int off = 32; off; off >>= 1) s += __shfl_xor(s, off);
  if ((tid & 63) == 0) red[tid >> 6] = s;
  __syncthreads();
  s = red[0] + red[1] + red[2] + red[3];
  float mu = s * (1.0f / CC);
  float qs = 0.f;
#pragma unroll
  for (int j = 0; j < 3; ++j) { float d = v[j] - mu; qs += d * d; }
#pragma unroll
  for (int off = 32; off; off >>= 1) qs += __shfl_xor(qs, off);
  if ((tid & 63) == 0) red[4 + (tid >> 6)] = qs;
  __syncthreads();
  qs = red[4] + red[5] + red[6] + red[7];
  float rstd = rsqrtf(qs * (1.0f / CC) + 1e-5f);
#pragma unroll
  for (int j = 0; j < 3; ++j) {
    int c = tid + j * 256;
    float y = (v[j] - mu) * rstd * gw[c] + bw[c];
    if (WF32) outf[(size_t)row * CC + c] = y;
    if (WB16) outb[(size_t)row * CC + c] = f2b(y);
  }
}

extern "C" void kernel_launch(void* const* d_in, const int* in_sizes, int n_in,
                              void* d_out, int out_size, void* d_ws, size_t ws_size,
                              hipStream_t stream) {
  (void)in_sizes; (void)n_in; (void)out_size; (void)ws_size;
  const float* x    = (const float*)d_in[0];
  const float* Wqkv = (const float*)d_in[1];
  const float* bqkv = (const float*)d_in[2];
  const float* Wo   = (const float*)d_in[3];
  const float* bo   = (const float*)d_in[4];
  const float* ln1g = (const float*)d_in[5];
  const float* ln1b = (const float*)d_in[6];
  const float* Wf   = (const float*)d_in[7];
  const float* bf_  = (const float*)d_in[8];
  const float* Wp   = (const float*)d_in[9];
  const float* bp   = (const float*)d_in[10];
  const float* ln2g = (const float*)d_in[11];
  const float* ln2b = (const float*)d_in[12];

  char* ws = (char*)d_ws;
  size_t off = 0;
  auto alloc = [&](size_t bytes) {
    void* p = ws + off;
    off += (bytes + 255) & ~(size_t)255;
    return p;
  };
  unsigned short* xb    = (unsigned short*)alloc((size_t)TBT * CC * 2);
  unsigned short* WqkvT = (unsigned short*)alloc((size_t)3 * CC * CC * 2);
  unsigned short* WoT   = (unsigned short*)alloc((size_t)CC * CC * 2);
  unsigned short* WfT   = (unsigned short*)alloc((size_t)4 * CC * CC * 2);
  unsigned short* WpT   = (unsigned short*)alloc((size_t)4 * CC * CC * 2);
  unsigned short* qkvb  = (unsigned short*)alloc((size_t)TBT * 3 * CC * 2);
  unsigned short* VTb   = (unsigned short*)alloc((size_t)TBT * CC * 2);
  float*          hbuf  = (float*)alloc((size_t)TBT * CC * 4);
  float*          hln   = (float*)alloc((size_t)TBT * CC * 4);
  unsigned short* hlnb  = (unsigned short*)alloc((size_t)TBT * CC * 2);
  unsigned short* gbuf  = (unsigned short*)alloc((size_t)TBT * 4 * CC * 2);
  unsigned short* aout  = xb;    // xb dead after GEMM1
  float*          h2    = hbuf;  // hbuf dead after LN1

  k_f32_to_bf16<<<(TBT * CC) / 1024, 256, 0, stream>>>(x, xb, TBT * CC);
  k_transpose_w<<<dim3(3 * CC / 32, CC / 32), 256, 0, stream>>>(Wqkv, WqkvT, CC, 3 * CC);
  k_transpose_w<<<dim3(CC / 32, CC / 32), 256, 0, stream>>>(Wo, WoT, CC, CC);
  k_transpose_w<<<dim3(4 * CC / 32, CC / 32), 256, 0, stream>>>(Wf, WfT, CC, 4 * CC);
  k_transpose_w<<<dim3(CC / 32, 4 * CC / 32), 256, 0, stream>>>(Wp, WpT, 4 * CC, CC);

  // qkv = x @ Wqkv + bqkv   -> bf16 [4096, 2304]
  k_gemm_bt<0><<<dim3(3 * CC / 128, TBT / 128), 256, 0, stream>>>(
      xb, WqkvT, bqkv, nullptr, qkvb, nullptr, TBT, 3 * CC, CC);
  // VT[b,h,d,t]
  k_vtrans<<<dim3(TT / 32, DD / 32, BB * HH), 256, 0, stream>>>(qkvb, VTb);
  // attention -> aout bf16 [4096, 768]
  k_attn<<<dim3(TT / 64, BB * HH), 256, 0, stream>>>(qkvb, VTb, aout);
  // h = x + attn @ Wo + bo  -> f32
  k_gemm_bt<2><<<dim3(CC / 128, TBT / 128), 256, 0, stream>>>(
      aout, WoT, bo, x, nullptr, hbuf, TBT, CC, CC);
  // LN1 -> hln (f32) + hlnb (bf16)
  k_layernorm<1, 1><<<TBT, 256, 0, stream>>>(hbuf, ln1g, ln1b, hln, hlnb);
  // g = gelu(hln @ Wf + bf) -> bf16 [4096, 3072]
  k_gemm_bt<1><<<dim3(4 * CC / 128, TBT / 128), 256, 0, stream>>>(
      hlnb, WfT, bf_, nullptr, gbuf, nullptr, TBT, 4 * CC, CC);
  // h2 = hln + g @ Wp + bp  -> f32
  k_gemm_bt<2><<<dim3(CC / 128, TBT / 128), 256, 0, stream>>>(
      gbuf, WpT, bp, hln, nullptr, h2, TBT, CC, 4 * CC);
  // LN2 -> d_out (f32)
  k_layernorm<1, 0><<<TBT, 256, 0, stream>>>(h2, ln2g, ln2b, (float*)d_out, nullptr);
}

// Round 4
// 253.845 us; speedup vs baseline: 1.4838x; 1.0815x over previous
//
#include <hip/hip_runtime.h>

#define BB 2
#define TT 2048
#define CC 768
#define HH 12
#define DD 64
#define TBT (BB * TT)   // 4096 rows

typedef __bf16 bfx8 __attribute__((ext_vector_type(8)));
typedef float f32x4 __attribute__((ext_vector_type(4)));
typedef float f32x16 __attribute__((ext_vector_type(16)));

__device__ __forceinline__ unsigned short f2b(float f) {
  unsigned u = __float_as_uint(f);
  return (unsigned short)((u + 0x7FFFu + ((u >> 16) & 1u)) >> 16);
}

__device__ __forceinline__ unsigned pack2bf(float lo, float hi) {
  union { __bf16 h[2]; unsigned u; } x;
  x.h[0] = (__bf16)lo; x.h[1] = (__bf16)hi;
  return x.u;   // compiler emits v_cvt_pk_bf16_f32
}

__device__ __forceinline__ void gload_lds16(const void* g, void* l) {
  __builtin_amdgcn_global_load_lds((const __attribute__((address_space(1))) void*)g,
                                   (__attribute__((address_space(3))) void*)l, 16, 0, 0);
}

// ---------------- f32 -> bf16 elementwise (vectorized) ----------------
__global__ __launch_bounds__(256) void k_f32_to_bf16(const float* __restrict__ in,
                                                     unsigned short* __restrict__ out, int n) {
  int i = (blockIdx.x * 256 + threadIdx.x) * 4;
  if (i + 3 < n) {
    float4 v = *(const float4*)(in + i);
    ushort4 o;
    o.x = f2b(v.x); o.y = f2b(v.y); o.z = f2b(v.z); o.w = f2b(v.w);
    *(ushort4*)(out + i) = o;
  }
}

// ---------------- W [K,N] f32  ->  WT [N,K] bf16 (LDS tiled) ----------------
__global__ __launch_bounds__(256) void k_transpose_w(const float* __restrict__ W,
                                                     unsigned short* __restrict__ WT,
                                                     int K, int N) {
  __shared__ float tile[32][33];
  int n0 = blockIdx.x * 32, k0 = blockIdx.y * 32;
  int j = threadIdx.x & 31, i0 = threadIdx.x >> 5;
  for (int i = i0; i < 32; i += 8) tile[i][j] = W[(size_t)(k0 + i) * N + n0 + j];
  __syncthreads();
  for (int i = i0; i < 32; i += 8) WT[(size_t)(n0 + i) * K + k0 + j] = f2b(tile[j][i]);
}

// ---------------- GEMM: C[M,N] = A[M,K] @ B[K,N],  Bt given as [N,K] ----------------
template<int MODE>
__global__ __launch_bounds__(256) void k_gemm_bt(const unsigned short* __restrict__ A,
                                                 const unsigned short* __restrict__ Bt,
                                                 const float* __restrict__ bias,
                                                 const float* __restrict__ resid,
                                                 unsigned short* __restrict__ outb,
                                                 float* __restrict__ outf,
                                                 int M, int N, int K) {
  __shared__ __align__(16) unsigned short As[128 * 64];
  __shared__ __align__(16) unsigned short Bs[128 * 64];
  const int tid = threadIdx.x;
  const int l = tid & 63, w = tid >> 6;
  const int wr = w >> 1, wc = w & 1;
  const int lr = l & 15, g = l >> 4;
  const int m0 = blockIdx.y * 128, n0 = blockIdx.x * 128;

  f32x4 acc[4][4] = {};

  for (int kt = 0; kt < K; kt += 64) {
#pragma unroll
    for (int i = 0; i < 4; ++i) {
      int s = tid + i * 256;           // 16B slot index, 0..1023
      int row = s >> 3;
      int q = (s & 7) ^ (row & 7);     // inverse-swizzled global source (linear LDS dest)
      gload_lds16(A + (size_t)(m0 + row) * K + kt + q * 8, &As[s * 8]);
      gload_lds16(Bt + (size_t)(n0 + row) * K + kt + q * 8, &Bs[s * 8]);
    }
    __syncthreads();
#pragma unroll
    for (int kk = 0; kk < 2; ++kk) {
      bfx8 af[4], bfr[4];
#pragma unroll
      for (int m = 0; m < 4; ++m) {
        int row = wr * 64 + m * 16 + lr;
        int quad = (kk * 4 + g) ^ (row & 7);
        af[m] = *(const bfx8*)(&As[row * 64 + quad * 8]);
      }
#pragma unroll
      for (int n = 0; n < 4; ++n) {
        int row = wc * 64 + n * 16 + lr;
        int quad = (kk * 4 + g) ^ (row & 7);
        bfr[n] = *(const bfx8*)(&Bs[row * 64 + quad * 8]);
      }
#pragma unroll
      for (int m = 0; m < 4; ++m)
#pragma unroll
        for (int n = 0; n < 4; ++n)
          acc[m][n] = __builtin_amdgcn_mfma_f32_16x16x32_bf16(af[m], bfr[n], acc[m][n], 0, 0, 0);
    }
    __syncthreads();
  }

#pragma unroll
  for (int m = 0; m < 4; ++m) {
#pragma unroll
    for (int n = 0; n < 4; ++n) {
      int col = n0 + wc * 64 + n * 16 + lr;
      float bv = bias[col];
#pragma unroll
      for (int r = 0; r < 4; ++r) {
        int row = m0 + wr * 64 + m * 16 + g * 4 + r;
        float v = acc[m][n][r] + bv;
        if (MODE == 1) v = 0.5f * v * (1.0f + erff(v * 0.70710678118654752440f));
        if (MODE == 2) {
          v += resid[(size_t)row * N + col];
          outf[(size_t)row * N + col] = v;
        } else {
          outb[(size_t)row * N + col] = f2b(v);
        }
      }
    }
  }
}

// ---------------- V transpose (LDS tiled): qkv bf16 -> VT[b,h,d,t] bf16 ----------------
__global__ __launch_bounds__(256) void k_vtrans(const unsigned short* __restrict__ qkv,
                                                unsigned short* __restrict__ VT) {
  __shared__ unsigned short tile[32][33];
  int t0 = blockIdx.x * 32, d0 = blockIdx.y * 32, bh = blockIdx.z;
  int b = bh / HH, h = bh % HH;
  int j = threadIdx.x & 31, i0 = threadIdx.x >> 5;
  for (int i = i0; i < 32; i += 8)
    tile[i][j] = qkv[(size_t)(b * TT + t0 + i) * (3 * CC) + 2 * CC + h * DD + d0 + j];
  __syncthreads();
  for (int i = i0; i < 32; i += 8)
    VT[((size_t)(bh * DD + d0 + i)) * TT + t0 + j] = tile[j][i];
}

// ---------------- causal flash attention: 32x32x16 swapped-operand structure ----------------
// mfma(K,Q) -> S^T (lane owns full P-row for q=lane&31); in-register P repack via
// cvt_pk + v_permlane32_swap; PV as O^T = mfma(V^T, P^T). 4 waves x 32 q-rows = 128 q/block.
__global__ __launch_bounds__(256) void k_attn(const unsigned short* __restrict__ qkv,
                                              const unsigned short* __restrict__ VT,
                                              unsigned short* __restrict__ aout) {
  __shared__ __align__(16) unsigned short Ks[2][64 * 64];
  __shared__ __align__(16) unsigned short Vs[2][64 * 64];
  const int tid = threadIdx.x;
  const int l = tid & 63, w = tid >> 6;
  const int ql = l & 31, hi = l >> 5;
  const int bh = blockIdx.y;
  const int b = bh / HH, h = bh % HH;
  // balance swizzle: pair long+short blocks (work 2bx+2; pairs sum to 34)
  const int tx = blockIdx.x;
  const int bx = (tx & 1) ? (15 - (tx >> 1)) : (tx >> 1);
  const int q0 = bx * 128;
  const int qw = q0 + w * 32;          // this wave's 32 q-rows
  const int qrow = qw + ql;

  const unsigned short* Kbase = qkv + (size_t)(b * TT) * (3 * CC) + CC + h * DD;
  const unsigned short* Vbase = VT + (size_t)bh * DD * TT;

  // Q as B-operand frags (col=q=lane&31, kd = c*16 + hi*8 + j), pre-scaled to log2 domain
  bfx8 qf[4];
  {
    const unsigned short* qp = qkv + (size_t)(b * TT + qrow) * (3 * CC) + h * DD;
    const float SC = 0.125f * 1.44269504088896340736f;   // 1/sqrt(D) * log2(e)
#pragma unroll
    for (int c = 0; c < 4; ++c) {
      bfx8 rw = *(const bfx8*)(qp + c * 16 + hi * 8);
#pragma unroll
      for (int j = 0; j < 8; ++j) qf[c][j] = (__bf16)((float)rw[j] * SC);
    }
  }

  f32x16 o0 = {}, o1 = {};       // O^T accs: d-halves 0/1 (col=q, row=d within 32)
  float m_run = -1e30f, l_run = 0.f;

  const int nt = 2 * bx + 2;

  auto stage = [&](int t, int bufi) {
    const int k0 = t * 64;
#pragma unroll
    for (int i = 0; i < 2; ++i) {
      int s = tid + i * 256;          // 16B slot, 0..511
      int row = s >> 3;
      int q = (s & 7) ^ (row & 7);    // inverse-swizzled source, linear LDS dest
      gload_lds16(Kbase + (size_t)(k0 + row) * (3 * CC) + q * 8, &Ks[bufi][s * 8]);
      gload_lds16(Vbase + (size_t)row * TT + k0 + q * 8, &Vs[bufi][s * 8]);
    }
  };

  stage(0, 0);
  __syncthreads();

  int cur = 0;
  for (int t = 0; t < nt; ++t) {
    const int k0 = t * 64;
    if (t + 1 < nt) stage(t + 1, cur ^ 1);   // prefetch overlaps compute

    if (k0 <= qw + 31) {   // wave-uniform: skip fully-masked tiles
      // ---- QK^T (swapped): sa[kh] = S^T for k-rows kh*32..kh*32+31 ----
      f32x16 sa[2];
      __builtin_amdgcn_s_setprio(1);
#pragma unroll
      for (int kh = 0; kh < 2; ++kh) {
        f32x16 acc = {};
        int row = kh * 32 + ql;
        int rx = row & 7;
#pragma unroll
        for (int c = 0; c < 4; ++c) {
          int quad = (c * 2 + hi) ^ rx;
          bfx8 kf = *(const bfx8*)(&Ks[cur][row * 64 + quad * 8]);
          acc = __builtin_amdgcn_mfma_f32_32x32x16_bf16(kf, qf[c], acc, 0, 0, 0);
        }
        sa[kh] = acc;
      }
      __builtin_amdgcn_s_setprio(0);

      // ---- causal mask (only diagonal-region tiles) ----
      if (k0 + 63 > qw) {
#pragma unroll
        for (int kh = 0; kh < 2; ++kh)
#pragma unroll
          for (int r = 0; r < 16; ++r) {
            int kk = k0 + kh * 32 + (r & 3) + 8 * (r >> 2) + 4 * hi;
            if (kk > qrow) sa[kh][r] = -1e30f;
          }
      }

      // ---- row max over k: in-lane 32 + one cross-half shfl ----
      float mx = sa[0][0];
#pragma unroll
      for (int r = 1; r < 16; ++r) mx = fmaxf(mx, sa[0][r]);
#pragma unroll
      for (int r = 0; r < 16; ++r) mx = fmaxf(mx, sa[1][r]);
      mx = fmaxf(mx, __shfl_xor(mx, 32));

      // ---- defer-max rescale (log2 domain, thr ~ e^7.6) ----
      if (__any(mx > m_run + 11.0f)) {
        float mn = fmaxf(m_run, mx);
        float al = __builtin_amdgcn_exp2f(m_run - mn);
        m_run = mn;
        l_run *= al;
        o0 *= al;
        o1 *= al;
      }

      // ---- p = exp2(s - m), row sum, pack to bf16 pairs ----
      float rs = 0.f;
      unsigned pk[2][8];
#pragma unroll
      for (int kh = 0; kh < 2; ++kh)
#pragma unroll
        for (int i = 0; i < 8; ++i) {
          float p0 = __builtin_amdgcn_exp2f(sa[kh][2 * i] - m_run);
          float p1 = __builtin_amdgcn_exp2f(sa[kh][2 * i + 1] - m_run);
          rs += p0 + p1;
          pk[kh][i] = pack2bf(p0, p1);
        }
      rs += __shfl_xor(rs, 32);
      l_run += rs;

      // ---- in-register P^T -> B-frags via permlane32_swap ----
      // chunk kc = kh*2+c covers k = kc*16..kc*16+15; frag words:
      // swap(L0,M0) -> {w0,w2}; swap(L1,M1) -> {w1,w3}
      bfx8 pf[4];
#pragma unroll
      for (int kh = 0; kh < 2; ++kh)
#pragma unroll
        for (int c = 0; c < 2; ++c) {
          unsigned a0 = pk[kh][c * 4 + 0], a1 = pk[kh][c * 4 + 1];
          unsigned b0 = pk[kh][c * 4 + 2], b1 = pk[kh][c * 4 + 3];
          asm volatile("v_permlane32_swap_b32 %0, %1" : "+v"(a0), "+v"(b0));
          asm volatile("v_permlane32_swap_b32 %0, %1" : "+v"(a1), "+v"(b1));
          union { unsigned u[4]; bfx8 v; } cvt;
          cvt.u[0] = a0; cvt.u[1] = a1; cvt.u[2] = b0; cvt.u[3] = b1;
          pf[kh * 2 + c] = cvt.v;
        }

      // ---- PV: O^T[dhalf] += V^T-frag x P^T-frag over 4 k-chunks ----
      __builtin_amdgcn_s_setprio(1);
#pragma unroll
      for (int kc = 0; kc < 4; ++kc) {
        {
          int row = ql;
          bfx8 vf = *(const bfx8*)(&Vs[cur][row * 64 + (((kc * 2 + hi) ^ (row & 7)) * 8)]);
          o0 = __builtin_amdgcn_mfma_f32_32x32x16_bf16(vf, pf[kc], o0, 0, 0, 0);
        }
        {
          int row = 32 + ql;
          bfx8 vf = *(const bfx8*)(&Vs[cur][row * 64 + (((kc * 2 + hi) ^ (row & 7)) * 8)]);
          o1 = __builtin_amdgcn_mfma_f32_32x32x16_bf16(vf, pf[kc], o1, 0, 0, 0);
        }
      }
      __builtin_amdgcn_s_setprio(0);
    }

    __syncthreads();   // drains prefetch + all waves done with buf[cur]
    cur ^= 1;
  }

  // ---- epilogue: O[q][d] = O^T/l, packed 4-wide stores ----
  float inv = 1.0f / l_run;
  unsigned short* orow = aout + (size_t)(b * TT + qrow) * CC + h * DD;
#pragma unroll
  for (int dh = 0; dh < 2; ++dh) {
    const f32x16& oo = dh ? o1 : o0;
#pragma unroll
    for (int qd = 0; qd < 4; ++qd) {   // regs qd*4..qd*4+3 -> d = dh*32 + 8*qd + 4*hi + 0..3
      ushort4 v;
      v.x = f2b(oo[qd * 4 + 0] * inv);
      v.y = f2b(oo[qd * 4 + 1] * inv);
      v.z = f2b(oo[qd * 4 + 2] * inv);
      v.w = f2b(oo[qd * 4 + 3] * inv);
      *(ushort4*)(orow + dh * 32 + 8 * qd + 4 * hi) = v;
    }
  }
}

// ---------------- LayerNorm over C=768, one block per row ----------------
template<int WF32, int WB16>
__global__ __launch_bounds__(256) void k_layernorm(const float* __restrict__ in,
                                                   const float* __restrict__ gw,
                                                   const float* __restrict__ bw,
                                                   float* __restrict__ outf,
                                                   unsigned short* __restrict__ outb) {
  __shared__ float red[8];
  const int row = blockIdx.x;
  const float* x = in + (size_t)row * CC;
  const int tid = threadIdx.x;
  float v[3];
  float s = 0.f;
#pragma unroll
  for (int j = 0; j < 3; ++j) { v[j] = x[tid + j * 256]; s += v[j]; }
#pragma unroll
  for (int off = 32; off; off >>= 1) s += __shfl_xor(s, off);
  if ((tid & 63) == 0) red[tid >> 6] = s;
  __syncthreads();
  s = red[0] + red[1] + red[2] + red[3];
  float mu = s * (1.0f / CC);
  float qs = 0.f;
#pragma unroll
  for (int j = 0; j < 3; ++j) { float d = v[j] - mu; qs += d * d; }
#pragma unroll
  for (int off = 32; off; off >>= 1) qs += __shfl_xor(qs, off);
  if ((tid & 63) == 0) red[4 + (tid >> 6)] = qs;
  __syncthreads();
  qs = red[4] + red[5] + red[6] + red[7];
  float rstd = rsqrtf(qs * (1.0f / CC) + 1e-5f);
#pragma unroll
  for (int j = 0; j < 3; ++j) {
    int c = tid + j * 256;
    float y = (v[j] - mu) * rstd * gw[c] + bw[c];
    if (WF32) outf[(size_t)row * CC + c] = y;
    if (WB16) outb[(size_t)row * CC + c] = f2b(y);
  }
}

extern "C" void kernel_launch(void* const* d_in, const int* in_sizes, int n_in,
                              void* d_out, int out_size, void* d_ws, size_t ws_size,
                              hipStream_t stream) {
  (void)in_sizes; (void)n_in; (void)out_size; (void)ws_size;
  const float* x    = (const float*)d_in[0];
  const float* Wqkv = (const float*)d_in[1];
  const float* bqkv = (const float*)d_in[2];
  const float* Wo   = (const float*)d_in[3];
  const float* bo   = (const float*)d_in[4];
  const float* ln1g = (const float*)d_in[5];
  const float* ln1b = (const float*)d_in[6];
  const float* Wf   = (const float*)d_in[7];
  const float* bf_  = (const float*)d_in[8];
  const float* Wp   = (const float*)d_in[9];
  const float* bp   = (const float*)d_in[10];
  const float* ln2g = (const float*)d_in[11];
  const float* ln2b = (const float*)d_in[12];

  char* ws = (char*)d_ws;
  size_t off = 0;
  auto alloc = [&](size_t bytes) {
    void* p = ws + off;
    off += (bytes + 255) & ~(size_t)255;
    return p;
  };
  unsigned short* xb    = (unsigned short*)alloc((size_t)TBT * CC * 2);
  unsigned short* WqkvT = (unsigned short*)alloc((size_t)3 * CC * CC * 2);
  unsigned short* WoT   = (unsigned short*)alloc((size_t)CC * CC * 2);
  unsigned short* WfT   = (unsigned short*)alloc((size_t)4 * CC * CC * 2);
  unsigned short* WpT   = (unsigned short*)alloc((size_t)4 * CC * CC * 2);
  unsigned short* qkvb  = (unsigned short*)alloc((size_t)TBT * 3 * CC * 2);
  unsigned short* VTb   = (unsigned short*)alloc((size_t)TBT * CC * 2);
  float*          hbuf  = (float*)alloc((size_t)TBT * CC * 4);
  float*          hln   = (float*)alloc((size_t)TBT * CC * 4);
  unsigned short* hlnb  = (unsigned short*)alloc((size_t)TBT * CC * 2);
  unsigned short* gbuf  = (unsigned short*)alloc((size_t)TBT * 4 * CC * 2);
  unsigned short* aout  = xb;    // xb dead after GEMM1
  float*          h2    = hbuf;  // hbuf dead after LN1

  k_f32_to_bf16<<<(TBT * CC) / 1024, 256, 0, stream>>>(x, xb, TBT * CC);
  k_transpose_w<<<dim3(3 * CC / 32, CC / 32), 256, 0, stream>>>(Wqkv, WqkvT, CC, 3 * CC);
  k_transpose_w<<<dim3(CC / 32, CC / 32), 256, 0, stream>>>(Wo, WoT, CC, CC);
  k_transpose_w<<<dim3(4 * CC / 32, CC / 32), 256, 0, stream>>>(Wf, WfT, CC, 4 * CC);
  k_transpose_w<<<dim3(CC / 32, 4 * CC / 32), 256, 0, stream>>>(Wp, WpT, 4 * CC, CC);

  // qkv = x @ Wqkv + bqkv   -> bf16 [4096, 2304]
  k_gemm_bt<0><<<dim3(3 * CC / 128, TBT / 128), 256, 0, stream>>>(
      xb, WqkvT, bqkv, nullptr, qkvb, nullptr, TBT, 3 * CC, CC);
  // VT[b,h,d,t]
  k_vtrans<<<dim3(TT / 32, DD / 32, BB * HH), 256, 0, stream>>>(qkvb, VTb);
  // attention -> aout bf16 [4096, 768]
  k_attn<<<dim3(TT / 128, BB * HH), 256, 0, stream>>>(qkvb, VTb, aout);
  // h = x + attn @ Wo + bo  -> f32
  k_gemm_bt<2><<<dim3(CC / 128, TBT / 128), 256, 0, stream>>>(
      aout, WoT, bo, x, nullptr, hbuf, TBT, CC, CC);
  // LN1 -> hln (f32) + hlnb (bf16)
  k_layernorm<1, 1><<<TBT, 256, 0, stream>>>(hbuf, ln1g, ln1b, hln, hlnb);
  // g = gelu(hln @ Wf + bf) -> bf16 [4096, 3072]
  k_gemm_bt<1><<<dim3(4 * CC / 128, TBT / 128), 256, 0, stream>>>(
      hlnb, WfT, bf_, nullptr, gbuf, nullptr, TBT, 4 * CC, CC);
  // h2 = hln + g @ Wp + bp  -> f32
  k_gemm_bt<2><<<dim3(CC / 128, TBT / 128), 256, 0, stream>>>(
      gbuf, WpT, bp, hln, nullptr, h2, TBT, CC, 4 * CC);
  // LN2 -> d_out (f32)
  k_layernorm<1, 0><<<TBT, 256, 0, stream>>>(h2, ln2g, ln2b, (float*)d_out, nullptr);
}

// Round 5
// 227.241 us; speedup vs baseline: 1.6575x; 1.1171x over previous
//
#include <hip/hip_runtime.h>

#define BB 2
#define TT 2048
#define CC 768
#define HH 12
#define DD 64
#define TBT (BB * TT)   // 4096 rows

typedef __bf16 bfx8 __attribute__((ext_vector_type(8)));
typedef float f32x4 __attribute__((ext_vector_type(4)));
typedef float f32x16 __attribute__((ext_vector_type(16)));

__device__ __forceinline__ unsigned short f2b(float f) {
  unsigned u = __float_as_uint(f);
  return (unsigned short)((u + 0x7FFFu + ((u >> 16) & 1u)) >> 16);
}
__device__ __forceinline__ float b2f(unsigned short u) {
  return __uint_as_float(((unsigned)u) << 16);
}

__device__ __forceinline__ unsigned pack2bf(float lo, float hi) {
  union { __bf16 h[2]; unsigned u; } x;
  x.h[0] = (__bf16)lo; x.h[1] = (__bf16)hi;
  return x.u;   // compiler emits v_cvt_pk_bf16_f32
}

__device__ __forceinline__ void gload_lds16(const void* g, void* l) {
  __builtin_amdgcn_global_load_lds((const __attribute__((address_space(1))) void*)g,
                                   (__attribute__((address_space(3))) void*)l, 16, 0, 0);
}

// ---------------- f32 -> bf16 elementwise (vectorized) ----------------
__global__ __launch_bounds__(256) void k_f32_to_bf16(const float* __restrict__ in,
                                                     unsigned short* __restrict__ out, int n) {
  int i = (blockIdx.x * 256 + threadIdx.x) * 4;
  if (i + 3 < n) {
    float4 v = *(const float4*)(in + i);
    ushort4 o;
    o.x = f2b(v.x); o.y = f2b(v.y); o.z = f2b(v.z); o.w = f2b(v.w);
    *(ushort4*)(out + i) = o;
  }
}

// ---------------- W [K,N] f32  ->  WT [N,K] bf16 (LDS tiled) ----------------
__global__ __launch_bounds__(256) void k_transpose_w(const float* __restrict__ W,
                                                     unsigned short* __restrict__ WT,
                                                     int K, int N) {
  __shared__ float tile[32][33];
  int n0 = blockIdx.x * 32, k0 = blockIdx.y * 32;
  int j = threadIdx.x & 31, i0 = threadIdx.x >> 5;
  for (int i = i0; i < 32; i += 8) tile[i][j] = W[(size_t)(k0 + i) * N + n0 + j];
  __syncthreads();
  for (int i = i0; i < 32; i += 8) WT[(size_t)(n0 + i) * K + k0 + j] = f2b(tile[j][i]);
}

// ---------------- GEMM: C[M,N] = A[M,K] @ B[K,N],  Bt given as [N,K] ----------------
// MODE 0: out = bf16(acc + bias)
// MODE 1: out = bf16(gelu(acc + bias))        (exact erf gelu)
// MODE 3: split-K over blockIdx.z (2 halves): raw f32 partial (no bias) -> outf0/outf1
template<int MODE>
__global__ __launch_bounds__(256) void k_gemm_bt(const unsigned short* __restrict__ A,
                                                 const unsigned short* __restrict__ Bt,
                                                 const float* __restrict__ bias,
                                                 unsigned short* __restrict__ outb,
                                                 float* __restrict__ outf0,
                                                 float* __restrict__ outf1,
                                                 int M, int N, int K) {
  __shared__ __align__(16) unsigned short As[128 * 64];
  __shared__ __align__(16) unsigned short Bs[128 * 64];
  const int tid = threadIdx.x;
  const int l = tid & 63, w = tid >> 6;
  const int wr = w >> 1, wc = w & 1;
  const int lr = l & 15, g = l >> 4;

  // bijective XCD-chunked swizzle over (x,y) (nwg % 8 == 0 for all our grids)
  const int gx = gridDim.x, nwg = gx * gridDim.y;
  const int orig = blockIdx.x + gx * blockIdx.y;
  const int q8 = nwg >> 3;
  const int swz = (orig & 7) * q8 + (orig >> 3);
  const int m0 = (swz / gx) * 128, n0 = (swz % gx) * 128;

  int kbeg = 0, kend = K;
  if (MODE == 3) { int K2 = K >> 1; kbeg = blockIdx.z * K2; kend = kbeg + K2; }

  f32x4 acc[4][4] = {};

  for (int kt = kbeg; kt < kend; kt += 64) {
#pragma unroll
    for (int i = 0; i < 4; ++i) {
      int s = tid + i * 256;           // 16B slot index, 0..1023
      int row = s >> 3;
      int q = (s & 7) ^ (row & 7);     // inverse-swizzled global source (linear LDS dest)
      gload_lds16(A + (size_t)(m0 + row) * K + kt + q * 8, &As[s * 8]);
      gload_lds16(Bt + (size_t)(n0 + row) * K + kt + q * 8, &Bs[s * 8]);
    }
    __syncthreads();
#pragma unroll
    for (int kk = 0; kk < 2; ++kk) {
      bfx8 af[4], bfr[4];
#pragma unroll
      for (int m = 0; m < 4; ++m) {
        int row = wr * 64 + m * 16 + lr;
        int quad = (kk * 4 + g) ^ (row & 7);
        af[m] = *(const bfx8*)(&As[row * 64 + quad * 8]);
      }
#pragma unroll
      for (int n = 0; n < 4; ++n) {
        int row = wc * 64 + n * 16 + lr;
        int quad = (kk * 4 + g) ^ (row & 7);
        bfr[n] = *(const bfx8*)(&Bs[row * 64 + quad * 8]);
      }
#pragma unroll
      for (int m = 0; m < 4; ++m)
#pragma unroll
        for (int n = 0; n < 4; ++n)
          acc[m][n] = __builtin_amdgcn_mfma_f32_16x16x32_bf16(af[m], bfr[n], acc[m][n], 0, 0, 0);
    }
    __syncthreads();
  }

  float* dst = (MODE == 3) ? (blockIdx.z ? outf1 : outf0) : nullptr;
#pragma unroll
  for (int m = 0; m < 4; ++m) {
#pragma unroll
    for (int n = 0; n < 4; ++n) {
      int col = n0 + wc * 64 + n * 16 + lr;
      float bv = (MODE == 3) ? 0.f : bias[col];
#pragma unroll
      for (int r = 0; r < 4; ++r) {
        int row = m0 + wr * 64 + m * 16 + g * 4 + r;
        float v = acc[m][n][r] + bv;
        if (MODE == 1) v = 0.5f * v * (1.0f + erff(v * 0.70710678118654752440f));
        if (MODE == 3) {
          dst[(size_t)row * N + col] = v;
        } else {
          outb[(size_t)row * N + col] = f2b(v);
        }
      }
    }
  }
}

// ---------------- V transpose (LDS tiled): qkv bf16 -> VT[b,h,d,t] bf16 ----------------
__global__ __launch_bounds__(256) void k_vtrans(const unsigned short* __restrict__ qkv,
                                                unsigned short* __restrict__ VT) {
  __shared__ unsigned short tile[32][33];
  int t0 = blockIdx.x * 32, d0 = blockIdx.y * 32, bh = blockIdx.z;
  int b = bh / HH, h = bh % HH;
  int j = threadIdx.x & 31, i0 = threadIdx.x >> 5;
  for (int i = i0; i < 32; i += 8)
    tile[i][j] = qkv[(size_t)(b * TT + t0 + i) * (3 * CC) + 2 * CC + h * DD + d0 + j];
  __syncthreads();
  for (int i = i0; i < 32; i += 8)
    VT[((size_t)(bh * DD + d0 + i)) * TT + t0 + j] = tile[j][i];
}

// ---------------- causal flash attention pass 1 (split-S over blockIdx.z) ----------------
// 32x32x16 swapped-operand; writes UNNORMALIZED bf16 O-partial + (m,l) per row.
__global__ __launch_bounds__(256) void k_attn(const unsigned short* __restrict__ qkv,
                                              const unsigned short* __restrict__ VT,
                                              unsigned short* __restrict__ opart,
                                              float2* __restrict__ ml) {
  __shared__ __align__(16) unsigned short Ks[2][64 * 64];
  __shared__ __align__(16) unsigned short Vs[2][64 * 64];
  const int tid = threadIdx.x;
  const int l = tid & 63, w = tid >> 6;
  const int ql = l & 31, hi = l >> 5;
  const int bh = blockIdx.y;
  const int b = bh / HH, h = bh % HH;
  const int s = blockIdx.z;
  // balance swizzle: pair long+short blocks
  const int tx = blockIdx.x;
  const int bx = (tx & 1) ? (15 - (tx >> 1)) : (tx >> 1);
  const int q0 = bx * 128;
  const int qw = q0 + w * 32;          // this wave's 32 q-rows
  const int qrow = qw + ql;

  const unsigned short* Kbase = qkv + (size_t)(b * TT) * (3 * CC) + CC + h * DD;
  const unsigned short* Vbase = VT + (size_t)bh * DD * TT;

  // Q as B-operand frags, pre-scaled to log2 domain
  bfx8 qf[4];
  {
    const unsigned short* qp = qkv + (size_t)(b * TT + qrow) * (3 * CC) + h * DD;
    const float SC = 0.125f * 1.44269504088896340736f;
#pragma unroll
    for (int c = 0; c < 4; ++c) {
      bfx8 rw = *(const bfx8*)(qp + c * 16 + hi * 8);
#pragma unroll
      for (int j = 0; j < 8; ++j) qf[c][j] = (__bf16)((float)rw[j] * SC);
    }
  }

  f32x16 o0 = {}, o1 = {};
  float m_run = -1e30f, l_run = 0.f;

  const int nloc = bx + 1;             // tiles per split
  const int t0i = s * nloc;            // first tile of this split

  auto stage = [&](int t, int bufi) {
    const int k0 = t * 64;
#pragma unroll
    for (int i = 0; i < 2; ++i) {
      int sl = tid + i * 256;
      int row = sl >> 3;
      int q = (sl & 7) ^ (row & 7);
      gload_lds16(Kbase + (size_t)(k0 + row) * (3 * CC) + q * 8, &Ks[bufi][sl * 8]);
      gload_lds16(Vbase + (size_t)row * TT + k0 + q * 8, &Vs[bufi][sl * 8]);
    }
  };

  stage(t0i, 0);
  __syncthreads();

  int cur = 0;
  for (int ti = 0; ti < nloc; ++ti) {
    const int t = t0i + ti;
    const int k0 = t * 64;
    if (ti + 1 < nloc) stage(t + 1, cur ^ 1);

    if (k0 <= qw + 31) {   // wave-uniform: skip fully-masked tiles
      f32x16 sa[2];
      __builtin_amdgcn_s_setprio(1);
#pragma unroll
      for (int kh = 0; kh < 2; ++kh) {
        f32x16 acc = {};
        int row = kh * 32 + ql;
        int rx = row & 7;
#pragma unroll
        for (int c = 0; c < 4; ++c) {
          int quad = (c * 2 + hi) ^ rx;
          bfx8 kf = *(const bfx8*)(&Ks[cur][row * 64 + quad * 8]);
          acc = __builtin_amdgcn_mfma_f32_32x32x16_bf16(kf, qf[c], acc, 0, 0, 0);
        }
        sa[kh] = acc;
      }
      __builtin_amdgcn_s_setprio(0);

      if (k0 + 63 > qw) {   // diagonal-region mask
#pragma unroll
        for (int kh = 0; kh < 2; ++kh)
#pragma unroll
          for (int r = 0; r < 16; ++r) {
            int kk = k0 + kh * 32 + (r & 3) + 8 * (r >> 2) + 4 * hi;
            if (kk > qrow) sa[kh][r] = -1e30f;
          }
      }

      float mx = sa[0][0];
#pragma unroll
      for (int r = 1; r < 16; ++r) mx = fmaxf(mx, sa[0][r]);
#pragma unroll
      for (int r = 0; r < 16; ++r) mx = fmaxf(mx, sa[1][r]);
      mx = fmaxf(mx, __shfl_xor(mx, 32));

      if (__any(mx > m_run + 11.0f)) {
        float mn = fmaxf(m_run, mx);
        float al = __builtin_amdgcn_exp2f(m_run - mn);
        m_run = mn;
        l_run *= al;
        o0 *= al;
        o1 *= al;
      }

      float rs = 0.f;
      unsigned pk[2][8];
#pragma unroll
      for (int kh = 0; kh < 2; ++kh)
#pragma unroll
        for (int i = 0; i < 8; ++i) {
          float p0 = __builtin_amdgcn_exp2f(sa[kh][2 * i] - m_run);
          float p1 = __builtin_amdgcn_exp2f(sa[kh][2 * i + 1] - m_run);
          rs += p0 + p1;
          pk[kh][i] = pack2bf(p0, p1);
        }
      rs += __shfl_xor(rs, 32);
      l_run += rs;

      bfx8 pf[4];
#pragma unroll
      for (int kh = 0; kh < 2; ++kh)
#pragma unroll
        for (int c = 0; c < 2; ++c) {
          unsigned a0 = pk[kh][c * 4 + 0], a1 = pk[kh][c * 4 + 1];
          unsigned b0 = pk[kh][c * 4 + 2], b1 = pk[kh][c * 4 + 3];
          asm volatile("v_permlane32_swap_b32 %0, %1" : "+v"(a0), "+v"(b0));
          asm volatile("v_permlane32_swap_b32 %0, %1" : "+v"(a1), "+v"(b1));
          union { unsigned u[4]; bfx8 v; } cvt;
          cvt.u[0] = a0; cvt.u[1] = a1; cvt.u[2] = b0; cvt.u[3] = b1;
          pf[kh * 2 + c] = cvt.v;
        }

      __builtin_amdgcn_s_setprio(1);
#pragma unroll
      for (int kc = 0; kc < 4; ++kc) {
        {
          int row = ql;
          bfx8 vf = *(const bfx8*)(&Vs[cur][row * 64 + (((kc * 2 + hi) ^ (row & 7)) * 8)]);
          o0 = __builtin_amdgcn_mfma_f32_32x32x16_bf16(vf, pf[kc], o0, 0, 0, 0);
        }
        {
          int row = 32 + ql;
          bfx8 vf = *(const bfx8*)(&Vs[cur][row * 64 + (((kc * 2 + hi) ^ (row & 7)) * 8)]);
          o1 = __builtin_amdgcn_mfma_f32_32x32x16_bf16(vf, pf[kc], o1, 0, 0, 0);
        }
      }
      __builtin_amdgcn_s_setprio(0);
    }

    __syncthreads();
    cur ^= 1;
  }

  // ---- epilogue: write UNNORMALIZED O-partial (bf16) + (m,l) ----
  unsigned short* orow = opart + (size_t)s * TBT * CC + (size_t)(b * TT + qrow) * CC + h * DD;
#pragma unroll
  for (int dh = 0; dh < 2; ++dh) {
    const f32x16& oo = dh ? o1 : o0;
#pragma unroll
    for (int qd = 0; qd < 4; ++qd) {
      ushort4 v;
      v.x = f2b(oo[qd * 4 + 0]);
      v.y = f2b(oo[qd * 4 + 1]);
      v.z = f2b(oo[qd * 4 + 2]);
      v.w = f2b(oo[qd * 4 + 3]);
      *(ushort4*)(orow + dh * 32 + 8 * qd + 4 * hi) = v;
    }
  }
  if (hi == 0) ml[((size_t)s * (BB * HH) + bh) * TT + qrow] = make_float2(m_run, l_run);
}

// ---------------- attention combine: out = (w0*O0 + w1*O1) / (w0*l0 + w1*l1) ----------------
__global__ __launch_bounds__(256) void k_attn_combine(const unsigned short* __restrict__ opart,
                                                      const float2* __restrict__ ml,
                                                      unsigned short* __restrict__ aout) {
  int idx = (blockIdx.x * 256 + threadIdx.x) * 4;
  int bt = idx / CC, c = idx % CC;
  int b = bt >> 11, t = bt & (TT - 1);
  int h = c >> 6;
  int bh = b * HH + h;
  float2 ml0 = ml[(size_t)bh * TT + t];
  float2 ml1 = ml[((size_t)(BB * HH) + bh) * TT + t];
  float M = fmaxf(ml0.x, ml1.x);
  float w0 = __builtin_amdgcn_exp2f(ml0.x - M);
  float w1 = __builtin_amdgcn_exp2f(ml1.x - M);
  float linv = 1.0f / (w0 * ml0.y + w1 * ml1.y);
  ushort4 a = *(const ushort4*)(opart + idx);
  ushort4 bq = *(const ushort4*)(opart + (size_t)TBT * CC + idx);
  ushort4 o;
  o.x = f2b((b2f(a.x) * w0 + b2f(bq.x) * w1) * linv);
  o.y = f2b((b2f(a.y) * w0 + b2f(bq.y) * w1) * linv);
  o.z = f2b((b2f(a.z) * w0 + b2f(bq.z) * w1) * linv);
  o.w = f2b((b2f(a.w) * w0 + b2f(bq.w) * w1) * linv);
  *(ushort4*)(aout + idx) = o;
}

// ---------------- LayerNorm+combine over C=768: v = in0+in1+resid+bias, then LN ----------------
template<int WF32, int WB16>
__global__ __launch_bounds__(256) void k_layernorm_c(const float* __restrict__ in0,
                                                     const float* __restrict__ in1,
                                                     const float* __restrict__ resid,
                                                     const float* __restrict__ biasv,
                                                     const float* __restrict__ gw,
                                                     const float* __restrict__ bw,
                                                     float* __restrict__ outf,
                                                     unsigned short* __restrict__ outb) {
  __shared__ float red[8];
  const int row = blockIdx.x;
  const int tid = threadIdx.x;
  float v[3];
  float s = 0.f;
#pragma unroll
  for (int j = 0; j < 3; ++j) {
    int c = tid + j * 256;
    size_t idx = (size_t)row * CC + c;
    v[j] = in0[idx] + in1[idx] + resid[idx] + biasv[c];
    s += v[j];
  }
#pragma unroll
  for (int off = 32; off; off >>= 1) s += __shfl_xor(s, off);
  if ((tid & 63) == 0) red[tid >> 6] = s;
  __syncthreads();
  s = red[0] + red[1] + red[2] + red[3];
  float mu = s * (1.0f / CC);
  float qs = 0.f;
#pragma unroll
  for (int j = 0; j < 3; ++j) { float d = v[j] - mu; qs += d * d; }
#pragma unroll
  for (int off = 32; off; off >>= 1) qs += __shfl_xor(qs, off);
  if ((tid & 63) == 0) red[4 + (tid >> 6)] = qs;
  __syncthreads();
  qs = red[4] + red[5] + red[6] + red[7];
  float rstd = rsqrtf(qs * (1.0f / CC) + 1e-5f);
#pragma unroll
  for (int j = 0; j < 3; ++j) {
    int c = tid + j * 256;
    float y = (v[j] - mu) * rstd * gw[c] + bw[c];
    if (WF32) outf[(size_t)row * CC + c] = y;
    if (WB16) outb[(size_t)row * CC + c] = f2b(y);
  }
}

extern "C" void kernel_launch(void* const* d_in, const int* in_sizes, int n_in,
                              void* d_out, int out_size, void* d_ws, size_t ws_size,
                              hipStream_t stream) {
  (void)in_sizes; (void)n_in; (void)out_size; (void)ws_size;
  const float* x    = (const float*)d_in[0];
  const float* Wqkv = (const float*)d_in[1];
  const float* bqkv = (const float*)d_in[2];
  const float* Wo   = (const float*)d_in[3];
  const float* bo   = (const float*)d_in[4];
  const float* ln1g = (const float*)d_in[5];
  const float* ln1b = (const float*)d_in[6];
  const float* Wf   = (const float*)d_in[7];
  const float* bf_  = (const float*)d_in[8];
  const float* Wp   = (const float*)d_in[9];
  const float* bp   = (const float*)d_in[10];
  const float* ln2g = (const float*)d_in[11];
  const float* ln2b = (const float*)d_in[12];

  char* ws = (char*)d_ws;
  size_t off = 0;
  auto alloc = [&](size_t bytes) {
    void* p = ws + off;
    off += (bytes + 255) & ~(size_t)255;
    return p;
  };
  unsigned short* xb    = (unsigned short*)alloc((size_t)TBT * CC * 2);
  unsigned short* WqkvT = (unsigned short*)alloc((size_t)3 * CC * CC * 2);
  unsigned short* WoT   = (unsigned short*)alloc((size_t)CC * CC * 2);
  unsigned short* WfT   = (unsigned short*)alloc((size_t)4 * CC * CC * 2);
  unsigned short* WpT   = (unsigned short*)alloc((size_t)4 * CC * CC * 2);
  unsigned short* qkvb  = (unsigned short*)alloc((size_t)TBT * 3 * CC * 2);
  unsigned short* VTb   = (unsigned short*)alloc((size_t)TBT * CC * 2);
  float*          hbuf  = (float*)alloc((size_t)TBT * CC * 4);
  float*          hln   = (float*)alloc((size_t)TBT * CC * 4);
  unsigned short* hlnb  = (unsigned short*)alloc((size_t)TBT * CC * 2);
  unsigned short* gbuf  = (unsigned short*)alloc((size_t)TBT * 4 * CC * 2);

  // aliases (lifetime-disjoint):
  unsigned short* aout  = xb;                               // attn final out (xb dead after QKV GEMM)
  unsigned short* opart = gbuf;                             // attn O-partials, 2 x 6.3MB bf16 (gbuf free pre-FFN1)
  float2*         mlbuf = (float2*)hbuf;                    // attn (m,l), 2 x 24 x 2048 (hbuf free here)
  float*          woP0  = (float*)gbuf;                     // Wo split-K partials (opart dead after combine)
  float*          woP1  = (float*)((char*)gbuf + (size_t)TBT * CC * 4);
  float*          fpP0  = hbuf;                             // FFN2 split-K partials (mlbuf dead after combine)
  float*          fpP1  = (float*)qkvb;                     // (qkvb dead after attention pass 1)

  k_f32_to_bf16<<<(TBT * CC) / 1024, 256, 0, stream>>>(x, xb, TBT * CC);
  k_transpose_w<<<dim3(3 * CC / 32, CC / 32), 256, 0, stream>>>(Wqkv, WqkvT, CC, 3 * CC);
  k_transpose_w<<<dim3(CC / 32, CC / 32), 256, 0, stream>>>(Wo, WoT, CC, CC);
  k_transpose_w<<<dim3(4 * CC / 32, CC / 32), 256, 0, stream>>>(Wf, WfT, CC, 4 * CC);
  k_transpose_w<<<dim3(CC / 32, 4 * CC / 32), 256, 0, stream>>>(Wp, WpT, 4 * CC, CC);

  // qkv = x @ Wqkv + bqkv   -> bf16 [4096, 2304]
  k_gemm_bt<0><<<dim3(3 * CC / 128, TBT / 128), 256, 0, stream>>>(
      xb, WqkvT, bqkv, qkvb, nullptr, nullptr, TBT, 3 * CC, CC);
  // VT[b,h,d,t]
  k_vtrans<<<dim3(TT / 32, DD / 32, BB * HH), 256, 0, stream>>>(qkvb, VTb);
  // attention pass 1 (split-S=2) -> opart, ml
  k_attn<<<dim3(TT / 128, BB * HH, 2), 256, 0, stream>>>(qkvb, VTb, opart, mlbuf);
  // combine -> aout bf16
  k_attn_combine<<<(TBT * CC) / 1024, 256, 0, stream>>>(opart, mlbuf, aout);
  // attn @ Wo (split-K=2) -> woP0/woP1 f32 partials
  k_gemm_bt<3><<<dim3(CC / 128, TBT / 128, 2), 256, 0, stream>>>(
      aout, WoT, nullptr, nullptr, woP0, woP1, TBT, CC, CC);
  // LN1( woP0+woP1 + x + bo ) -> hln (f32) + hlnb (bf16)
  k_layernorm_c<1, 1><<<TBT, 256, 0, stream>>>(woP0, woP1, x, bo, ln1g, ln1b, hln, hlnb);
  // g = gelu(hln @ Wf + bf) -> bf16 [4096, 3072]
  k_gemm_bt<1><<<dim3(4 * CC / 128, TBT / 128), 256, 0, stream>>>(
      hlnb, WfT, bf_, gbuf, nullptr, nullptr, TBT, 4 * CC, CC);
  // g @ Wp (split-K=2) -> fpP0/fpP1 f32 partials
  k_gemm_bt<3><<<dim3(CC / 128, TBT / 128, 2), 256, 0, stream>>>(
      gbuf, WpT, nullptr, nullptr, fpP0, fpP1, TBT, CC, 4 * CC);
  // LN2( fpP0+fpP1 + hln + bp ) -> d_out (f32)
  k_layernorm_c<1, 0><<<TBT, 256, 0, stream>>>(fpP0, fpP1, hln, bp, ln2g, ln2b,
                                               (float*)d_out, nullptr);
}

// Round 7
// 213.366 us; speedup vs baseline: 1.7653x; 1.0650x over previous
//
#include <hip/hip_runtime.h>

#define BB 2
#define TT 2048
#define CC 768
#define HH 12
#define DD 64
#define TBT (BB * TT)   // 4096 rows

typedef __bf16 bfx8 __attribute__((ext_vector_type(8)));
typedef float f32x4 __attribute__((ext_vector_type(4)));
typedef float f32x16 __attribute__((ext_vector_type(16)));

__device__ __forceinline__ unsigned short f2b(float f) {
  unsigned u = __float_as_uint(f);
  return (unsigned short)((u + 0x7FFFu + ((u >> 16) & 1u)) >> 16);
}
__device__ __forceinline__ float b2f(unsigned short u) {
  return __uint_as_float(((unsigned)u) << 16);
}

__device__ __forceinline__ unsigned pack2bf(float lo, float hi) {
  union { __bf16 h[2]; unsigned u; } x;
  x.h[0] = (__bf16)lo; x.h[1] = (__bf16)hi;
  return x.u;   // compiler emits v_cvt_pk_bf16_f32
}

__device__ __forceinline__ void gload_lds16(const void* g, void* l) {
  __builtin_amdgcn_global_load_lds((const __attribute__((address_space(1))) void*)g,
                                   (__attribute__((address_space(3))) void*)l, 16, 0, 0);
}

// ---------------- f32 -> bf16 elementwise (vectorized) ----------------
__global__ __launch_bounds__(256) void k_f32_to_bf16(const float* __restrict__ in,
                                                     unsigned short* __restrict__ out, int n) {
  int i = (blockIdx.x * 256 + threadIdx.x) * 4;
  if (i + 3 < n) {
    float4 v = *(const float4*)(in + i);
    ushort4 o;
    o.x = f2b(v.x); o.y = f2b(v.y); o.z = f2b(v.z); o.w = f2b(v.w);
    *(ushort4*)(out + i) = o;
  }
}

// ---------------- W [K,N] f32  ->  WT [N,K] bf16 (LDS tiled) ----------------
__global__ __launch_bounds__(256) void k_transpose_w(const float* __restrict__ W,
                                                     unsigned short* __restrict__ WT,
                                                     int K, int N) {
  __shared__ float tile[32][33];
  int n0 = blockIdx.x * 32, k0 = blockIdx.y * 32;
  int j = threadIdx.x & 31, i0 = threadIdx.x >> 5;
  for (int i = i0; i < 32; i += 8) tile[i][j] = W[(size_t)(k0 + i) * N + n0 + j];
  __syncthreads();
  for (int i = i0; i < 32; i += 8) WT[(size_t)(n0 + i) * K + k0 + j] = f2b(tile[j][i]);
}

// ---------------- GEMM: C[M,N] = A[M,K] @ B[K,N],  Bt given as [N,K] ----------------
// MODE 0: out = bf16(acc + bias)
// MODE 1: out = bf16(gelu(acc + bias))        (exact erf gelu)
// MODE 3: split-K over blockIdx.z (2 halves): raw f32 partial (no bias) -> outf0/outf1
template<int MODE>
__global__ __launch_bounds__(256) void k_gemm_bt(const unsigned short* __restrict__ A,
                                                 const unsigned short* __restrict__ Bt,
                                                 const float* __restrict__ bias,
                                                 unsigned short* __restrict__ outb,
                                                 float* __restrict__ outf0,
                                                 float* __restrict__ outf1,
                                                 int M, int N, int K) {
  __shared__ __align__(16) unsigned short As[128 * 64];
  __shared__ __align__(16) unsigned short Bs[128 * 64];
  const int tid = threadIdx.x;
  const int l = tid & 63, w = tid >> 6;
  const int wr = w >> 1, wc = w & 1;
  const int lr = l & 15, g = l >> 4;

  // bijective XCD-chunked swizzle over (x,y) (nwg % 8 == 0 for all our grids)
  const int gx = gridDim.x, nwg = gx * gridDim.y;
  const int orig = blockIdx.x + gx * blockIdx.y;
  const int q8 = nwg >> 3;
  const int swz = (orig & 7) * q8 + (orig >> 3);
  const int m0 = (swz / gx) * 128, n0 = (swz % gx) * 128;

  int kbeg = 0, kend = K;
  if (MODE == 3) { int K2 = K >> 1; kbeg = blockIdx.z * K2; kend = kbeg + K2; }

  f32x4 acc[4][4] = {};

  for (int kt = kbeg; kt < kend; kt += 64) {
#pragma unroll
    for (int i = 0; i < 4; ++i) {
      int s = tid + i * 256;           // 16B slot index, 0..1023
      int row = s >> 3;
      int q = (s & 7) ^ (row & 7);     // inverse-swizzled global source (linear LDS dest)
      gload_lds16(A + (size_t)(m0 + row) * K + kt + q * 8, &As[s * 8]);
      gload_lds16(Bt + (size_t)(n0 + row) * K + kt + q * 8, &Bs[s * 8]);
    }
    __syncthreads();
#pragma unroll
    for (int kk = 0; kk < 2; ++kk) {
      bfx8 af[4], bfr[4];
#pragma unroll
      for (int m = 0; m < 4; ++m) {
        int row = wr * 64 + m * 16 + lr;
        int quad = (kk * 4 + g) ^ (row & 7);
        af[m] = *(const bfx8*)(&As[row * 64 + quad * 8]);
      }
#pragma unroll
      for (int n = 0; n < 4; ++n) {
        int row = wc * 64 + n * 16 + lr;
        int quad = (kk * 4 + g) ^ (row & 7);
        bfr[n] = *(const bfx8*)(&Bs[row * 64 + quad * 8]);
      }
#pragma unroll
      for (int m = 0; m < 4; ++m)
#pragma unroll
        for (int n = 0; n < 4; ++n)
          acc[m][n] = __builtin_amdgcn_mfma_f32_16x16x32_bf16(af[m], bfr[n], acc[m][n], 0, 0, 0);
    }
    __syncthreads();
  }

  float* dst = (MODE == 3) ? (blockIdx.z ? outf1 : outf0) : nullptr;
#pragma unroll
  for (int m = 0; m < 4; ++m) {
#pragma unroll
    for (int n = 0; n < 4; ++n) {
      int col = n0 + wc * 64 + n * 16 + lr;
      float bv = (MODE == 3) ? 0.f : bias[col];
#pragma unroll
      for (int r = 0; r < 4; ++r) {
        int row = m0 + wr * 64 + m * 16 + g * 4 + r;
        float v = acc[m][n][r] + bv;
        if (MODE == 1) v = 0.5f * v * (1.0f + erff(v * 0.70710678118654752440f));
        if (MODE == 3) {
          dst[(size_t)row * N + col] = v;
        } else {
          outb[(size_t)row * N + col] = f2b(v);
        }
      }
    }
  }
}

// ---------------- V transpose (LDS tiled): qkv bf16 -> VT[b,h,d,t] bf16 ----------------
__global__ __launch_bounds__(256) void k_vtrans(const unsigned short* __restrict__ qkv,
                                                unsigned short* __restrict__ VT) {
  __shared__ unsigned short tile[32][33];
  int t0 = blockIdx.x * 32, d0 = blockIdx.y * 32, bh = blockIdx.z;
  int b = bh / HH, h = bh % HH;
  int j = threadIdx.x & 31, i0 = threadIdx.x >> 5;
  for (int i = i0; i < 32; i += 8)
    tile[i][j] = qkv[(size_t)(b * TT + t0 + i) * (3 * CC) + 2 * CC + h * DD + d0 + j];
  __syncthreads();
  for (int i = i0; i < 32; i += 8)
    VT[((size_t)(bh * DD + d0 + i)) * TT + t0 + j] = tile[j][i];
}

// ---------------- causal flash attention pass 1 (work-uniform k-chunks) ----------------
// Each (bh, q-block bx) causal range of nt=2bx+2 tiles is cut into chunks of <=8 tiles.
// 40 chunks per bh -> grid (40, 24). Single-chunk q-blocks (bx<4) write normalized output
// directly; multi-chunk write unnormalized bf16 O-partial + (m,l).
// Reductions use the R5-proven __shfl_xor forms.
__global__ __launch_bounds__(256) void k_attn(const unsigned short* __restrict__ qkv,
                                              const unsigned short* __restrict__ VT,
                                              unsigned short* __restrict__ aout,
                                              unsigned short* __restrict__ opart,
                                              float2* __restrict__ ml) {
  __shared__ __align__(16) unsigned short Ks[2][64 * 64];
  __shared__ __align__(16) unsigned short Vs[2][64 * 64];
  const int tid = threadIdx.x;
  const int l = tid & 63, w = tid >> 6;
  const int ql = l & 31, hi = l >> 5;
  const int bh = blockIdx.y;
  const int b = bh / HH, h = bh % HH;

  // decode chunk id -> (bx, sub)
  const int cid = blockIdx.x;
  int bx, sub;
  if (cid < 4)       { bx = cid;                  sub = 0; }
  else if (cid < 12) { bx = 4 + ((cid - 4) >> 1); sub = (cid - 4) & 1; }
  else if (cid < 24) { bx = 8 + (cid - 12) / 3;   sub = (cid - 12) % 3; }
  else               { bx = 12 + ((cid - 24) >> 2); sub = (cid - 24) & 3; }
  const int nt = 2 * bx + 2;
  const int nchunks = (nt + 7) >> 3;
  const int t0i = sub * 8;
  const int tcount = min(8, nt - t0i);

  const int qw = bx * 128 + w * 32;    // this wave's 32 q-rows
  const int qrow = qw + ql;

  const unsigned short* Kbase = qkv + (size_t)(b * TT) * (3 * CC) + CC + h * DD;
  const unsigned short* Vbase = VT + (size_t)bh * DD * TT;

  // Q as B-operand frags, pre-scaled to log2 domain
  bfx8 qf[4];
  {
    const unsigned short* qp = qkv + (size_t)(b * TT + qrow) * (3 * CC) + h * DD;
    const float SC = 0.125f * 1.44269504088896340736f;
#pragma unroll
    for (int c = 0; c < 4; ++c) {
      bfx8 rw = *(const bfx8*)(qp + c * 16 + hi * 8);
#pragma unroll
      for (int j = 0; j < 8; ++j) qf[c][j] = (__bf16)((float)rw[j] * SC);
    }
  }

  f32x16 o0 = {}, o1 = {};
  float m_run = -1e30f, l_run = 0.f;

  auto stage = [&](int t, int bufi) {
    const int k0 = t * 64;
#pragma unroll
    for (int i = 0; i < 2; ++i) {
      int sl = tid + i * 256;
      int row = sl >> 3;
      int q = (sl & 7) ^ (row & 7);
      gload_lds16(Kbase + (size_t)(k0 + row) * (3 * CC) + q * 8, &Ks[bufi][sl * 8]);
      gload_lds16(Vbase + (size_t)row * TT + k0 + q * 8, &Vs[bufi][sl * 8]);
    }
  };

  stage(t0i, 0);
  __syncthreads();

  int cur = 0;
  for (int ti = 0; ti < tcount; ++ti) {
    const int t = t0i + ti;
    const int k0 = t * 64;
    if (ti + 1 < tcount) stage(t + 1, cur ^ 1);

    if (k0 <= qw + 31) {   // wave-uniform: skip fully-masked tiles
      f32x16 sa[2];
      __builtin_amdgcn_s_setprio(1);
#pragma unroll
      for (int kh = 0; kh < 2; ++kh) {
        f32x16 acc = {};
        int row = kh * 32 + ql;
        int rx = row & 7;
#pragma unroll
        for (int c = 0; c < 4; ++c) {
          int quad = (c * 2 + hi) ^ rx;
          bfx8 kf = *(const bfx8*)(&Ks[cur][row * 64 + quad * 8]);
          acc = __builtin_amdgcn_mfma_f32_32x32x16_bf16(kf, qf[c], acc, 0, 0, 0);
        }
        sa[kh] = acc;
      }
      __builtin_amdgcn_s_setprio(0);

      if (k0 + 63 > qw) {   // diagonal-region mask
#pragma unroll
        for (int kh = 0; kh < 2; ++kh)
#pragma unroll
          for (int r = 0; r < 16; ++r) {
            int kk = k0 + kh * 32 + (r & 3) + 8 * (r >> 2) + 4 * hi;
            if (kk > qrow) sa[kh][r] = -1e30f;
          }
      }

      // ---- row max over k (R5-proven form) ----
      float mx = sa[0][0];
#pragma unroll
      for (int r = 1; r < 16; ++r) mx = fmaxf(mx, sa[0][r]);
#pragma unroll
      for (int r = 0; r < 16; ++r) mx = fmaxf(mx, sa[1][r]);
      mx = fmaxf(mx, __shfl_xor(mx, 32));

      // ---- defer-max rescale (log2 domain) ----
      if (__any(mx > m_run + 11.0f)) {
        float mn = fmaxf(m_run, mx);
        float al = __builtin_amdgcn_exp2f(m_run - mn);
        m_run = mn;
        l_run *= al;
        o0 *= al;
        o1 *= al;
      }

      // ---- p = exp2(s - m), row sum, pack to bf16 pairs (R5-proven form) ----
      float rs = 0.f;
      unsigned pk[2][8];
#pragma unroll
      for (int kh = 0; kh < 2; ++kh)
#pragma unroll
        for (int i = 0; i < 8; ++i) {
          float p0 = __builtin_amdgcn_exp2f(sa[kh][2 * i] - m_run);
          float p1 = __builtin_amdgcn_exp2f(sa[kh][2 * i + 1] - m_run);
          rs += p0 + p1;
          pk[kh][i] = pack2bf(p0, p1);
        }
      rs += __shfl_xor(rs, 32);
      l_run += rs;

      // ---- in-register P^T -> B-frags via permlane32_swap ----
      bfx8 pf[4];
#pragma unroll
      for (int kh = 0; kh < 2; ++kh)
#pragma unroll
        for (int c = 0; c < 2; ++c) {
          unsigned a0 = pk[kh][c * 4 + 0], a1 = pk[kh][c * 4 + 1];
          unsigned b0 = pk[kh][c * 4 + 2], b1 = pk[kh][c * 4 + 3];
          asm volatile("v_permlane32_swap_b32 %0, %1" : "+v"(a0), "+v"(b0));
          asm volatile("v_permlane32_swap_b32 %0, %1" : "+v"(a1), "+v"(b1));
          union { unsigned u[4]; bfx8 v; } cvt;
          cvt.u[0] = a0; cvt.u[1] = a1; cvt.u[2] = b0; cvt.u[3] = b1;
          pf[kh * 2 + c] = cvt.v;
        }

      __builtin_amdgcn_s_setprio(1);
#pragma unroll
      for (int kc = 0; kc < 4; ++kc) {
        {
          int row = ql;
          bfx8 vf = *(const bfx8*)(&Vs[cur][row * 64 + (((kc * 2 + hi) ^ (row & 7)) * 8)]);
          o0 = __builtin_amdgcn_mfma_f32_32x32x16_bf16(vf, pf[kc], o0, 0, 0, 0);
        }
        {
          int row = 32 + ql;
          bfx8 vf = *(const bfx8*)(&Vs[cur][row * 64 + (((kc * 2 + hi) ^ (row & 7)) * 8)]);
          o1 = __builtin_amdgcn_mfma_f32_32x32x16_bf16(vf, pf[kc], o1, 0, 0, 0);
        }
      }
      __builtin_amdgcn_s_setprio(0);
    }

    __syncthreads();
    cur ^= 1;
  }

  if (nchunks == 1) {
    // single chunk covers the whole causal range: write normalized output directly
    float inv = 1.0f / l_run;
    unsigned short* orow = aout + (size_t)(b * TT + qrow) * CC + h * DD;
#pragma unroll
    for (int dh = 0; dh < 2; ++dh) {
      const f32x16& oo = dh ? o1 : o0;
#pragma unroll
      for (int qd = 0; qd < 4; ++qd) {
        ushort4 v;
        v.x = f2b(oo[qd * 4 + 0] * inv);
        v.y = f2b(oo[qd * 4 + 1] * inv);
        v.z = f2b(oo[qd * 4 + 2] * inv);
        v.w = f2b(oo[qd * 4 + 3] * inv);
        *(ushort4*)(orow + dh * 32 + 8 * qd + 4 * hi) = v;
      }
    }
  } else {
    unsigned short* orow = opart + (size_t)sub * TBT * CC + (size_t)(b * TT + qrow) * CC + h * DD;
#pragma unroll
    for (int dh = 0; dh < 2; ++dh) {
      const f32x16& oo = dh ? o1 : o0;
#pragma unroll
      for (int qd = 0; qd < 4; ++qd) {
        ushort4 v;
        v.x = f2b(oo[qd * 4 + 0]);
        v.y = f2b(oo[qd * 4 + 1]);
        v.z = f2b(oo[qd * 4 + 2]);
        v.w = f2b(oo[qd * 4 + 3]);
        *(ushort4*)(orow + dh * 32 + 8 * qd + 4 * hi) = v;
      }
    }
    if (hi == 0) ml[((size_t)sub * (BB * HH) + bh) * TT + qrow] = make_float2(m_run, l_run);
  }
}

// ---------------- attention combine: merge up to 4 unnormalized partials ----------------
__global__ __launch_bounds__(256) void k_attn_combine(const unsigned short* __restrict__ opart,
                                                      const float2* __restrict__ ml,
                                                      unsigned short* __restrict__ aout) {
  int idx = (blockIdx.x * 256 + threadIdx.x) * 4;
  int bt = idx / CC, c = idx % CC;
  int b = bt >> 11, t = bt & (TT - 1);
  int bx = t >> 7;
  int cnt = (2 * bx + 9) >> 3;
  if (cnt < 2) return;                       // single-chunk rows written by pass 1
  int h = c >> 6;
  int bh = b * HH + h;

  float2 mls[4] = {{-1e30f, 0.f}, {-1e30f, 0.f}, {-1e30f, 0.f}, {-1e30f, 0.f}};
  float M = -1e30f;
#pragma unroll
  for (int s = 0; s < 4; ++s)
    if (s < cnt) { mls[s] = ml[((size_t)s * (BB * HH) + bh) * TT + t]; M = fmaxf(M, mls[s].x); }
  float ww[4], lsum = 0.f;
#pragma unroll
  for (int s = 0; s < 4; ++s) {
    ww[s] = (s < cnt) ? __builtin_amdgcn_exp2f(mls[s].x - M) : 0.f;
    lsum += ww[s] * mls[s].y;
  }
  float linv = 1.0f / lsum;

  float a0 = 0.f, a1 = 0.f, a2 = 0.f, a3 = 0.f;
#pragma unroll
  for (int s = 0; s < 4; ++s)
    if (s < cnt) {
      ushort4 v = *(const ushort4*)(opart + (size_t)s * TBT * CC + idx);
      a0 += b2f(v.x) * ww[s];
      a1 += b2f(v.y) * ww[s];
      a2 += b2f(v.z) * ww[s];
      a3 += b2f(v.w) * ww[s];
    }
  ushort4 o;
  o.x = f2b(a0 * linv);
  o.y = f2b(a1 * linv);
  o.z = f2b(a2 * linv);
  o.w = f2b(a3 * linv);
  *(ushort4*)(aout + idx) = o;
}

// ---------------- LayerNorm+combine over C=768: v = in0+in1+resid+bias, then LN ----------------
template<int WF32, int WB16>
__global__ __launch_bounds__(256) void k_layernorm_c(const float* __restrict__ in0,
                                                     const float* __restrict__ in1,
                                                     const float* __restrict__ resid,
                                                     const float* __restrict__ biasv,
                                                     const float* __restrict__ gw,
                                                     const float* __restrict__ bw,
                                                     float* __restrict__ outf,
                                                     unsigned short* __restrict__ outb) {
  __shared__ float red[8];
  const int row = blockIdx.x;
  const int tid = threadIdx.x;
  float v[3];
  float s = 0.f;
#pragma unroll
  for (int j = 0; j < 3; ++j) {
    int c = tid + j * 256;
    size_t idx = (size_t)row * CC + c;
    v[j] = in0[idx] + in1[idx] + resid[idx] + biasv[c];
    s += v[j];
  }
#pragma unroll
  for (int off = 32; off; off >>= 1) s += __shfl_xor(s, off);
  if ((tid & 63) == 0) red[tid >> 6] = s;
  __syncthreads();
  s = red[0] + red[1] + red[2] + red[3];
  float mu = s * (1.0f / CC);
  float qs = 0.f;
#pragma unroll
  for (int j = 0; j < 3; ++j) { float d = v[j] - mu; qs += d * d; }
#pragma unroll
  for (int off = 32; off; off >>= 1) qs += __shfl_xor(qs, off);
  if ((tid & 63) == 0) red[4 + (tid >> 6)] = qs;
  __syncthreads();
  qs = red[4] + red[5] + red[6] + red[7];
  float rstd = rsqrtf(qs * (1.0f / CC) + 1e-5f);
#pragma unroll
  for (int j = 0; j < 3; ++j) {
    int c = tid + j * 256;
    float y = (v[j] - mu) * rstd * gw[c] + bw[c];
    if (WF32) outf[(size_t)row * CC + c] = y;
    if (WB16) outb[(size_t)row * CC + c] = f2b(y);
  }
}

extern "C" void kernel_launch(void* const* d_in, const int* in_sizes, int n_in,
                              void* d_out, int out_size, void* d_ws, size_t ws_size,
                              hipStream_t stream) {
  (void)in_sizes; (void)n_in; (void)out_size; (void)ws_size;
  const float* x    = (const float*)d_in[0];
  const float* Wqkv = (const float*)d_in[1];
  const float* bqkv = (const float*)d_in[2];
  const float* Wo   = (const float*)d_in[3];
  const float* bo   = (const float*)d_in[4];
  const float* ln1g = (const float*)d_in[5];
  const float* ln1b = (const float*)d_in[6];
  const float* Wf   = (const float*)d_in[7];
  const float* bf_  = (const float*)d_in[8];
  const float* Wp   = (const float*)d_in[9];
  const float* bp   = (const float*)d_in[10];
  const float* ln2g = (const float*)d_in[11];
  const float* ln2b = (const float*)d_in[12];

  char* ws = (char*)d_ws;
  size_t off = 0;
  auto alloc = [&](size_t bytes) {
    void* p = ws + off;
    off += (bytes + 255) & ~(size_t)255;
    return p;
  };
  unsigned short* xb    = (unsigned short*)alloc((size_t)TBT * CC * 2);
  unsigned short* WqkvT = (unsigned short*)alloc((size_t)3 * CC * CC * 2);
  unsigned short* WoT   = (unsigned short*)alloc((size_t)CC * CC * 2);
  unsigned short* WfT   = (unsigned short*)alloc((size_t)4 * CC * CC * 2);
  unsigned short* WpT   = (unsigned short*)alloc((size_t)4 * CC * CC * 2);
  unsigned short* qkvb  = (unsigned short*)alloc((size_t)TBT * 3 * CC * 2);
  unsigned short* VTb   = (unsigned short*)alloc((size_t)TBT * CC * 2);
  float*          hbuf  = (float*)alloc((size_t)TBT * CC * 4);
  float*          hln   = (float*)alloc((size_t)TBT * CC * 4);
  unsigned short* hlnb  = (unsigned short*)alloc((size_t)TBT * CC * 2);
  unsigned short* gbuf  = (unsigned short*)alloc((size_t)TBT * 4 * CC * 2);

  // aliases (lifetime-disjoint):
  unsigned short* aout  = xb;                               // attn final out (xb dead after QKV GEMM)
  unsigned short* opart = gbuf;                             // attn O-partials, 4 x 6.3MB bf16 (gbuf free pre-FFN1)
  float2*         mlbuf = (float2*)hbuf;                    // attn (m,l), 4 x 24 x 2048 (hbuf free here)
  float*          woP0  = (float*)gbuf;                     // Wo split-K partials (opart dead after combine)
  float*          woP1  = (float*)((char*)gbuf + (size_t)TBT * CC * 4);
  float*          fpP0  = hbuf;                             // FFN2 split-K partials (mlbuf dead after combine)
  float*          fpP1  = (float*)qkvb;                     // (qkvb dead after attention pass 1)

  k_f32_to_bf16<<<(TBT * CC) / 1024, 256, 0, stream>>>(x, xb, TBT * CC);
  k_transpose_w<<<dim3(3 * CC / 32, CC / 32), 256, 0, stream>>>(Wqkv, WqkvT, CC, 3 * CC);
  k_transpose_w<<<dim3(CC / 32, CC / 32), 256, 0, stream>>>(Wo, WoT, CC, CC);
  k_transpose_w<<<dim3(4 * CC / 32, CC / 32), 256, 0, stream>>>(Wf, WfT, CC, 4 * CC);
  k_transpose_w<<<dim3(CC / 32, 4 * CC / 32), 256, 0, stream>>>(Wp, WpT, 4 * CC, CC);

  // qkv = x @ Wqkv + bqkv   -> bf16 [4096, 2304]
  k_gemm_bt<0><<<dim3(3 * CC / 128, TBT / 128), 256, 0, stream>>>(
      xb, WqkvT, bqkv, qkvb, nullptr, nullptr, TBT, 3 * CC, CC);
  // VT[b,h,d,t]
  k_vtrans<<<dim3(TT / 32, DD / 32, BB * HH), 256, 0, stream>>>(qkvb, VTb);
  // attention pass 1 (work-uniform chunks) -> aout (1-chunk rows) + opart/ml
  k_attn<<<dim3(40, BB * HH), 256, 0, stream>>>(qkvb, VTb, aout, opart, mlbuf);
  // combine multi-chunk rows -> aout bf16
  k_attn_combine<<<(TBT * CC) / 1024, 256, 0, stream>>>(opart, mlbuf, aout);
  // attn @ Wo (split-K=2) -> woP0/woP1 f32 partials
  k_gemm_bt<3><<<dim3(CC / 128, TBT / 128, 2), 256, 0, stream>>>(
      aout, WoT, nullptr, nullptr, woP0, woP1, TBT, CC, CC);
  // LN1( woP0+woP1 + x + bo ) -> hln (f32) + hlnb (bf16)
  k_layernorm_c<1, 1><<<TBT, 256, 0, stream>>>(woP0, woP1, x, bo, ln1g, ln1b, hln, hlnb);
  // g = gelu(hln @ Wf + bf) -> bf16 [4096, 3072]
  k_gemm_bt<1><<<dim3(4 * CC / 128, TBT / 128), 256, 0, stream>>>(
      hlnb, WfT, bf_, gbuf, nullptr, nullptr, TBT, 4 * CC, CC);
  // g @ Wp (split-K=2) -> fpP0/fpP1 f32 partials
  k_gemm_bt<3><<<dim3(CC / 128, TBT / 128, 2), 256, 0, stream>>>(
      gbuf, WpT, nullptr, nullptr, fpP0, fpP1, TBT, CC, 4 * CC);
  // LN2( fpP0+fpP1 + hln + bp ) -> d_out (f32)
  k_layernorm_c<1, 0><<<TBT, 256, 0, stream>>>(fpP0, fpP1, hln, bp, ln2g, ln2b,
                                               (float*)d_out, nullptr);
}